// Round 4
// baseline (966.876 us; speedup 1.0000x reference)
//
#include <hip/hip_runtime.h>
#include <hip/hip_bf16.h>
#include <hip/hip_cooperative_groups.h>

namespace cg = cooperative_groups;

typedef unsigned int uint_t;
typedef unsigned short ushort_t;
typedef __attribute__((ext_vector_type(8))) short short8;
typedef __attribute__((ext_vector_type(4))) float floatx4;

__device__ __forceinline__ float4 fma4(float4 a, float s, float4 w){
  a.x += s*w.x; a.y += s*w.y; a.z += s*w.z; a.w += s*w.w; return a;
}
__device__ __forceinline__ float4 relu4(float4 a){
  return make_float4(fmaxf(a.x,0.f),fmaxf(a.y,0.f),fmaxf(a.z,0.f),fmaxf(a.w,0.f));
}
__device__ __forceinline__ unsigned bf16rne(float f){
  unsigned u = __float_as_uint(f);
  return (u + 0x7fffu + ((u>>16)&1u)) >> 16;
}
__device__ __forceinline__ uint_t packbf(float f){
  unsigned hb = bf16rne(f);
  float hf = __uint_as_float(hb<<16);
  unsigned lb = bf16rne(f - hf);
  return (hb<<16) | lb;
}
__device__ __forceinline__ uint4 pack4(float4 v){
  uint4 u; u.x=packbf(v.x); u.y=packbf(v.y); u.z=packbf(v.z); u.w=packbf(v.w); return u;
}
#define UNPACK8(u0,u1,hi,lo) \
  hi[0]=(short)(u0.x>>16); lo[0]=(short)u0.x; \
  hi[1]=(short)(u0.y>>16); lo[1]=(short)u0.y; \
  hi[2]=(short)(u0.z>>16); lo[2]=(short)u0.z; \
  hi[3]=(short)(u0.w>>16); lo[3]=(short)u0.w; \
  hi[4]=(short)(u1.x>>16); lo[4]=(short)u1.x; \
  hi[5]=(short)(u1.y>>16); lo[5]=(short)u1.y; \
  hi[6]=(short)(u1.z>>16); lo[6]=(short)u1.z; \
  hi[7]=(short)(u1.w>>16); lo[7]=(short)u1.w;

// Fragment-order offset: off(n,k) = (n>>4)*16*K + (k>>5)*512 + (n&15)*32 + (k&31)

// heads GEMM K-window body: job (ks, ct in 0..7), 512 threads (8 waves = 8 row-blocks).
// Covers K tiles [k0c + ks*NKC, +NKC). Writes partial slot (slot0+ks).
template<int NKC>
__device__ __forceinline__ void hgemm_body(
    const uint_t* __restrict__ xcatpk,
    const ushort_t* __restrict__ qw1Thi, const ushort_t* __restrict__ qw1Tlo,
    const ushort_t* __restrict__ vw1Thi, const ushort_t* __restrict__ vw1Tlo,
    float* __restrict__ part, int ks, int ct, int t, int k0c, int slot0)
{
  const int w = t>>6, lane = t&63, m = lane&15, quad = lane>>4;
  const ushort_t* Bhi = (ct<4) ? qw1Thi : vw1Thi;
  const int cbl = (ct<4) ? ct*64 : (ct-4)*64;
  const int cbg = (ct<4) ? ct*64 : 256 + (ct-4)*64;
  const int kb = k0c + ks*NKC;
  const uint_t* ap = xcatpk + (size_t)w*18432 + m*32 + quad*8 + (size_t)kb*512;
  const ushort_t* bp0 = Bhi + (size_t)((cbl>>4)+0)*18432 + m*32 + quad*8 + (size_t)kb*512;
  const ushort_t* bp1 = Bhi + (size_t)((cbl>>4)+1)*18432 + m*32 + quad*8 + (size_t)kb*512;
  const ushort_t* bp2 = Bhi + (size_t)((cbl>>4)+2)*18432 + m*32 + quad*8 + (size_t)kb*512;
  const ushort_t* bp3 = Bhi + (size_t)((cbl>>4)+3)*18432 + m*32 + quad*8 + (size_t)kb*512;
  const size_t lod = (size_t)(qw1Tlo - qw1Thi);   // == vw1Tlo - vw1Thi by layout
  floatx4 acc[4];
  #pragma unroll
  for (int i=0;i<4;i++) acc[i] = (floatx4){0.f,0.f,0.f,0.f};
  #pragma unroll
  for (int kc=0; kc<NKC; kc++){
    const uint4 ua0 = *(const uint4*)(ap);
    const uint4 ua1 = *(const uint4*)(ap+4);
    ap += 512;
    short8 ahi, alo;
    UNPACK8(ua0,ua1,ahi,alo)
    const ushort_t* bps[4] = {bp0, bp1, bp2, bp3};
    #pragma unroll
    for (int nt=0; nt<4; nt++){
      const short8 bh = *(const short8*)(bps[nt] + kc*512);
      const short8 bl = *(const short8*)(bps[nt] + kc*512 + lod);
      acc[nt] = __builtin_amdgcn_mfma_f32_16x16x32_bf16(ahi, bh, acc[nt], 0,0,0);
      acc[nt] = __builtin_amdgcn_mfma_f32_16x16x32_bf16(ahi, bl, acc[nt], 0,0,0);
      acc[nt] = __builtin_amdgcn_mfma_f32_16x16x32_bf16(alo, bh, acc[nt], 0,0,0);
    }
  }
  float* pdst = part + (size_t)(slot0+ks)*65536;
  const int crow0 = w*16 + quad*4;
  #pragma unroll
  for (int nt=0; nt<4; nt++){
    const int col = cbg + nt*16 + m;
    #pragma unroll
    for (int r=0;r<4;r++)
      pdst[(size_t)(crow0 + r)*512 + col] = acc[nt][r];
  }
}

// =============== K1: enc (blocks 0..511, XCD-swizzled) + wl1/wr1 convert (512..639) ===============
__global__ __launch_bounds__(256) void prep_kernel(
    const float* __restrict__ obs,
    const float* __restrict__ enc_w1, const float* __restrict__ enc_b1,
    const float* __restrict__ enc_w2, const float* __restrict__ enc_b2,
    const float* __restrict__ wl1, const float* __restrict__ wr1,
    ushort_t* __restrict__ wl1Thi, ushort_t* __restrict__ wl1Tlo,
    ushort_t* __restrict__ wr1Thi, ushort_t* __restrict__ wr1Tlo,
    uint_t* __restrict__ xpk, uint_t* __restrict__ xcatpk,
    unsigned* __restrict__ adjw, int* __restrict__ aiw)
{
  const int t = threadIdx.x, bid = blockIdx.x;
  if (bid >= 512){
    __shared__ float sm[32][33];
    const int cw = bid - 512;
    const float* in; ushort_t* ohi; ushort_t* olo; int tt;
    const int K = 128, N = 512;
    if (cw < 64){ in=wl1; ohi=wl1Thi; olo=wl1Tlo; tt=cw; }
    else        { in=wr1; ohi=wr1Thi; olo=wr1Tlo; tt=cw-64; }
    const int ktiles = K>>5;
    const int kt = tt % ktiles, nt = tt / ktiles;
    const int r = t>>5, c = t&31;
    #pragma unroll
    for (int i=0;i<4;i++)
      sm[r+i*8][c] = in[(size_t)(kt*32 + r + i*8)*N + nt*32 + c];
    __syncthreads();
    #pragma unroll
    for (int i=0;i<4;i++){
      const int nl = r + i*8;
      const int n  = nt*32 + nl;
      const float f = sm[c][nl];
      const unsigned hb = bf16rne(f);
      const float hf = __uint_as_float(hb<<16);
      const unsigned lb = bf16rne(f - hf);
      const size_t off = (size_t)(n>>4)*(16*K) + (size_t)kt*512 + (size_t)(n&15)*32 + c;
      ohi[off] = (ushort_t)hb;
      olo[off] = (ushort_t)lb;
    }
    return;
  }
  __shared__ float s_pos[64];
  __shared__ float s_feats[128];
  __shared__ __align__(16) float s_h[8*132];
  __shared__ int s_ai;
  // XCD swizzle: same-sample blocks 128 apart -> same XCD (bid%8 preserved)
  const int s = bid & 127, g = bid >> 7;
  const float* ob = obs + s*577;

  if (t==0){
    float a = ob[576];
    a = fminf(fmaxf(a, 0.f), 31.f);
    s_ai = (int)a;
    if (g==0) aiw[s] = (int)a;
  }
  if (t < 128){ const int n=t>>4, f=t&15; s_feats[t] = ob[(g*8+n)*18+2+f]; }
  if (g==0 && t>=128 && t<192){ const int u=t-128; s_pos[u] = ob[(u>>1)*18 + (u&1)]; }
  __syncthreads();

  if (g==0 && t < 32){
    const float px = s_pos[2*t], py = s_pos[2*t+1];
    const float R2 = 0.09f;
    unsigned mm = 0u;
    for (int j=0;j<32;j++){
      const float dx = __fsub_rn(px, s_pos[2*j]), dy = __fsub_rn(py, s_pos[2*j+1]);
      const float d2 = __fadd_rn(__fmul_rn(dx,dx), __fmul_rn(dy,dy));
      if (d2 <= R2 || j==t) mm |= (1u<<j);
    }
    adjw[s*32+t] = mm;
  }

  const int n = t>>5, c0 = (t&31)*4;
  {
    float4 a = *(const float4*)(enc_b1+c0);
    #pragma unroll
    for (int f=0; f<16; f++)
      a = fma4(a, s_feats[n*16+f], *(const float4*)(enc_w1 + f*128 + c0));
    *(float4*)&s_h[n*132+c0] = relu4(a);
  }
  __syncthreads();
  {
    float4 a = *(const float4*)(enc_b2+c0);
    for (int k=0;k<128;k+=4){
      const float4 hv = *(const float4*)&s_h[n*132+k];
      a = fma4(a, hv.x, *(const float4*)(enc_w2 + (k+0)*128 + c0));
      a = fma4(a, hv.y, *(const float4*)(enc_w2 + (k+1)*128 + c0));
      a = fma4(a, hv.z, *(const float4*)(enc_w2 + (k+2)*128 + c0));
      a = fma4(a, hv.w, *(const float4*)(enc_w2 + (k+3)*128 + c0));
    }
    a = relu4(a);
    const uint4 p = pack4(a);
    const int i = g*8 + n;
    uint_t* xp = xpk + (size_t)(s*2 + (i>>4))*2048 + (c0>>5)*512 + (i&15)*32 + (c0&31);
    *(uint4*)xp = p;
    if (i == s_ai){
      uint_t* xc = xcatpk + (size_t)(s>>4)*18432 + (c0>>5)*512 + (s&15)*32 + (c0&31);
      *(uint4*)xc = p;
    }
  }
}

// ======== shared device bodies for phases (used by both mega and fallback kernels) ========

// GAT1 for (s,h): reads xpk + wl1T/wr1T, writes x2pk + xcat tap. Uses block LDS.
__device__ __forceinline__ void gat1_body(
    const uint_t* __restrict__ xpk,
    const ushort_t* __restrict__ wl1Thi, const ushort_t* __restrict__ wl1Tlo,
    const ushort_t* __restrict__ wr1Thi, const ushort_t* __restrict__ wr1Tlo,
    const float* __restrict__ att1, const float* __restrict__ bias1,
    const unsigned* __restrict__ adjw, const int* __restrict__ aiw,
    uint_t* __restrict__ x2pk, uint_t* __restrict__ xcatpk,
    float* s_gl, float* s_gr, float* s_att, float* s_b, float* s_lg, unsigned* s_adj,
    int s, int h, int t)
{
  const int w = t>>6, lane = t&63, m = lane&15, quad = lane>>4;
  const int mat = w>>2, cpair = w&3;

  if (t < 128){ s_att[t] = att1[h*128 + t]; s_b[t] = bias1[h*128 + t]; }
  if (t >= 224 && t < 256) s_adj[t-224] = adjw[s*32 + (t-224)];
  const int ai = aiw[s];

  const ushort_t* Bhi = (mat==0) ? wl1Thi : wr1Thi;
  const ushort_t* Blo = (mat==0) ? wl1Tlo : wr1Tlo;
  const int nbase = h*8 + cpair*2;
  const uint_t* a0p = xpk + (size_t)(s*2+0)*2048 + m*32 + quad*8;
  const uint_t* a1p = xpk + (size_t)(s*2+1)*2048 + m*32 + quad*8;
  const ushort_t* bp0 = Bhi + (size_t)(nbase+0)*2048 + m*32 + quad*8;
  const ushort_t* bp1 = Bhi + (size_t)(nbase+1)*2048 + m*32 + quad*8;
  const size_t lod = (size_t)(Blo - Bhi);
  floatx4 acc[2][2];
  #pragma unroll
  for (int i=0;i<2;i++)
    #pragma unroll
    for (int j=0;j<2;j++) acc[i][j] = (floatx4){0.f,0.f,0.f,0.f};

  #pragma unroll
  for (int kc=0; kc<4; kc++){
    const uint4 u00 = *(const uint4*)(a0p + kc*512);
    const uint4 u01 = *(const uint4*)(a0p + kc*512 + 4);
    const uint4 u10 = *(const uint4*)(a1p + kc*512);
    const uint4 u11 = *(const uint4*)(a1p + kc*512 + 4);
    short8 ahi0, alo0, ahi1, alo1;
    UNPACK8(u00,u01,ahi0,alo0)
    UNPACK8(u10,u11,ahi1,alo1)
    const ushort_t* bps[2] = {bp0, bp1};
    #pragma unroll
    for (int nt=0; nt<2; nt++){
      const short8 bh = *(const short8*)(bps[nt] + kc*512);
      const short8 bl = *(const short8*)(bps[nt] + kc*512 + lod);
      acc[0][nt] = __builtin_amdgcn_mfma_f32_16x16x32_bf16(ahi0, bh, acc[0][nt], 0,0,0);
      acc[0][nt] = __builtin_amdgcn_mfma_f32_16x16x32_bf16(ahi0, bl, acc[0][nt], 0,0,0);
      acc[0][nt] = __builtin_amdgcn_mfma_f32_16x16x32_bf16(alo0, bh, acc[0][nt], 0,0,0);
      acc[1][nt] = __builtin_amdgcn_mfma_f32_16x16x32_bf16(ahi1, bh, acc[1][nt], 0,0,0);
      acc[1][nt] = __builtin_amdgcn_mfma_f32_16x16x32_bf16(ahi1, bl, acc[1][nt], 0,0,0);
      acc[1][nt] = __builtin_amdgcn_mfma_f32_16x16x32_bf16(alo1, bh, acc[1][nt], 0,0,0);
    }
  }
  {
    float* dst = mat ? s_gr : s_gl;
    const int colbase = cpair*32;
    #pragma unroll
    for (int nt=0; nt<2; nt++){
      const int col = colbase + nt*16 + m;
      #pragma unroll
      for (int r=0;r<4;r++){
        dst[(quad*4+r)*132 + col]      = acc[0][nt][r];
        dst[(16+quad*4+r)*132 + col]   = acc[1][nt][r];
      }
    }
  }
  __syncthreads();

  // logits
  {
    const int i = t>>4, jb = t&15;
    float lacc[2] = {0.f,0.f};
    for (int c=0;c<128;c+=4){
      const float4 g = *(const float4*)&s_gr[i*132+c];
      const float4 a = *(const float4*)&s_att[c];
      #pragma unroll
      for (int mm=0;mm<2;mm++){
        const float4 gj = *(const float4*)&s_gl[(jb+16*mm)*132 + c];
        float ex = g.x+gj.x; ex = fmaxf(ex, 0.2f*ex);
        float ey = g.y+gj.y; ey = fmaxf(ey, 0.2f*ey);
        float ez = g.z+gj.z; ez = fmaxf(ez, 0.2f*ez);
        float ew = g.w+gj.w; ew = fmaxf(ew, 0.2f*ew);
        lacc[mm] += ex*a.x + ey*a.y + ez*a.z + ew*a.w;
      }
    }
    s_lg[i*33 + jb]      = lacc[0];
    s_lg[i*33 + jb + 16] = lacc[1];
  }
  __syncthreads();

  // masked softmax
  #pragma unroll
  for (int rnd=0; rnd<2; rnd++){
    const int i = rnd*16 + (t>>5), j = t&31;
    const float lg = s_lg[i*33+j];
    const bool ok = (s_adj[i]>>j)&1u;
    float v = ok ? lg : -3.0e38f;
    #pragma unroll
    for (int d_=16; d_; d_>>=1) v = fmaxf(v, __shfl_xor(v, d_, 32));
    const float e = ok ? __expf(lg - v) : 0.f;
    float sum = e;
    #pragma unroll
    for (int d_=16; d_; d_>>=1) sum += __shfl_xor(sum, d_, 32);
    s_lg[i*33+j] = e / sum;
  }
  __syncthreads();

  // aggregate -> packed x2 + tap
  {
    const int i = t>>4, c0 = (t&15)*8;
    float4 o0 = make_float4(0.f,0.f,0.f,0.f), o1 = o0;
    for (int j=0;j<32;j++){
      const float al = s_lg[i*33+j];
      o0 = fma4(o0, al, *(const float4*)&s_gl[j*132 + c0]);
      o1 = fma4(o1, al, *(const float4*)&s_gl[j*132 + c0 + 4]);
    }
    const float4 b0 = *(const float4*)&s_b[c0];
    const float4 b1 = *(const float4*)&s_b[c0+4];
    o0 = relu4(make_float4(o0.x+b0.x, o0.y+b0.y, o0.z+b0.z, o0.w+b0.w));
    o1 = relu4(make_float4(o1.x+b1.x, o1.y+b1.y, o1.z+b1.z, o1.w+b1.w));
    const uint4 p0 = pack4(o0), p1 = pack4(o1);
    const int kb = h*128 + c0;
    uint_t* xp = x2pk + (size_t)(s*2 + (i>>4))*8192 + (kb>>5)*512 + (i&15)*32 + (kb&31);
    *(uint4*)&xp[0] = p0;
    *(uint4*)&xp[4] = p1;
    if (i == ai){
      const int kk = 128 + kb;
      uint_t* tp = xcatpk + (size_t)(s>>4)*18432 + (kk>>5)*512 + (s&15)*32 + (kk&31);
      *(uint4*)&tp[0] = p0;
      *(uint4*)&tp[4] = p1;
    }
  }
}

// GR tile: GR[16 rows of tile rt, 16 cols of tile ctl]
__device__ __forceinline__ void gr_body(
    const uint_t* __restrict__ xcatpk,
    const ushort_t* __restrict__ wr2Thi, const ushort_t* __restrict__ wr2Tlo,
    float* __restrict__ GR, int ctl, int t)
{
  const int w = t>>6, lane = t&63, m = lane&15, quad = lane>>4;
  const uint_t* ap = xcatpk + (size_t)w*18432 + m*32 + quad*8 + (size_t)4*512;
  const ushort_t* bp = wr2Thi + (size_t)ctl*8192 + m*32 + quad*8;
  const size_t lod = (size_t)(wr2Tlo - wr2Thi);
  floatx4 acc = (floatx4){0.f,0.f,0.f,0.f};
  #pragma unroll 4
  for (int kc=0; kc<16; kc++){
    const uint4 ua0 = *(const uint4*)(ap + kc*512);
    const uint4 ua1 = *(const uint4*)(ap + kc*512 + 4);
    short8 ahi, alo;
    UNPACK8(ua0,ua1,ahi,alo)
    const short8 bh = *(const short8*)(bp + kc*512);
    const short8 bl = *(const short8*)(bp + kc*512 + lod);
    acc = __builtin_amdgcn_mfma_f32_16x16x32_bf16(ahi, bh, acc, 0,0,0);
    acc = __builtin_amdgcn_mfma_f32_16x16x32_bf16(ahi, bl, acc, 0,0,0);
    acc = __builtin_amdgcn_mfma_f32_16x16x32_bf16(alo, bh, acc, 0,0,0);
  }
  const int row0 = w*16 + quad*4, col = ctl*16 + m;
  #pragma unroll
  for (int r=0;r<4;r++)
    GR[(size_t)(row0 + r)*512 + col] = acc[r];
}

// GAT2 for (s,h): reads x2pk + wl2T + GR, writes xcat x3 slice. Uses block LDS.
__device__ __forceinline__ void gat2_body(
    const uint_t* __restrict__ x2pk,
    const ushort_t* __restrict__ wl2Thi, const ushort_t* __restrict__ wl2Tlo,
    const float* __restrict__ GR,
    const float* __restrict__ att2, const float* __restrict__ bias2,
    const unsigned* __restrict__ adjw, const int* __restrict__ aiw,
    uint_t* __restrict__ xcatpk,
    float* s_gl, float* p2, float* s_at, float* s_bb, float* lg32, float* al32,
    int s, int h, int t)
{
  const int w = t>>6, lane = t&63, m = lane&15, quad = lane>>4;
  (void)lane;
  const int ai = aiw[s];
  const unsigned arow = adjw[s*32+ai];

  if (t < 128){
    p2[t]   = GR[(size_t)s*512 + h*128 + t];
    s_at[t] = att2[h*128+t];
    s_bb[t] = bias2[h*128+t];
  }

  // gl2 = x2 @ wl2 : each wave owns one 16-col tile for full K=512.
  const uint_t* a0p = x2pk + (size_t)(s*2+0)*8192 + m*32 + quad*8;
  const uint_t* a1p = x2pk + (size_t)(s*2+1)*8192 + m*32 + quad*8;
  const ushort_t* bq = wl2Thi + (size_t)(h*8 + w)*8192 + m*32 + quad*8;
  const size_t lod = (size_t)(wl2Tlo - wl2Thi);
  floatx4 acc0 = (floatx4){0.f,0.f,0.f,0.f}, acc1 = acc0;
  #pragma unroll 4
  for (int kc=0; kc<16; kc++){
    const uint4 u00 = *(const uint4*)(a0p + kc*512);
    const uint4 u01 = *(const uint4*)(a0p + kc*512 + 4);
    const uint4 u10 = *(const uint4*)(a1p + kc*512);
    const uint4 u11 = *(const uint4*)(a1p + kc*512 + 4);
    short8 ahi0, alo0, ahi1, alo1;
    UNPACK8(u00,u01,ahi0,alo0)
    UNPACK8(u10,u11,ahi1,alo1)
    const short8 bh = *(const short8*)(bq + kc*512);
    const short8 bl = *(const short8*)(bq + kc*512 + lod);
    acc0 = __builtin_amdgcn_mfma_f32_16x16x32_bf16(ahi0, bh, acc0, 0,0,0);
    acc0 = __builtin_amdgcn_mfma_f32_16x16x32_bf16(ahi0, bl, acc0, 0,0,0);
    acc0 = __builtin_amdgcn_mfma_f32_16x16x32_bf16(alo0, bh, acc0, 0,0,0);
    acc1 = __builtin_amdgcn_mfma_f32_16x16x32_bf16(ahi1, bh, acc1, 0,0,0);
    acc1 = __builtin_amdgcn_mfma_f32_16x16x32_bf16(ahi1, bl, acc1, 0,0,0);
    acc1 = __builtin_amdgcn_mfma_f32_16x16x32_bf16(alo1, bh, acc1, 0,0,0);
  }
  {
    const int col = w*16 + m;
    #pragma unroll
    for (int r=0;r<4;r++){
      s_gl[(quad*4+r)*132 + col]    = acc0[r];
      s_gl[(16+quad*4+r)*132 + col] = acc1[r];
    }
  }
  __syncthreads();

  if (t < 256){
    const int j = t>>3, pq = t&7;
    float sum = 0.f;
    #pragma unroll
    for (int q=0;q<4;q++){
      const int c = pq*16 + q*4;
      const float4 g = *(const float4*)&s_gl[j*132 + c];
      const float4 r = *(const float4*)&p2[c];
      const float4 a = *(const float4*)&s_at[c];
      float e0 = r.x+g.x; e0 = fmaxf(e0, 0.2f*e0);
      float e1 = r.y+g.y; e1 = fmaxf(e1, 0.2f*e1);
      float e2 = r.z+g.z; e2 = fmaxf(e2, 0.2f*e2);
      float e3 = r.w+g.w; e3 = fmaxf(e3, 0.2f*e3);
      sum += e0*a.x + e1*a.y + e2*a.z + e3*a.w;
    }
    sum += __shfl_xor(sum,1,64);
    sum += __shfl_xor(sum,2,64);
    sum += __shfl_xor(sum,4,64);
    if (pq==0) lg32[j] = sum;
  }
  __syncthreads();
  if (t < 32){
    const float lg = lg32[t];
    const bool ok = (arow>>t)&1u;
    float v = ok ? lg : -3.0e38f;
    #pragma unroll
    for (int d_=16; d_; d_>>=1) v = fmaxf(v, __shfl_xor(v, d_, 32));
    const float e = ok ? __expf(lg - v) : 0.f;
    float sm = e;
    #pragma unroll
    for (int d_=16; d_; d_>>=1) sm += __shfl_xor(sm, d_, 32);
    al32[t] = e / sm;
  }
  __syncthreads();
  if (t < 128){
    float acc2 = 0.f;
    #pragma unroll 8
    for (int j=0;j<32;j++) acc2 += al32[j] * s_gl[j*132 + t];
    const float x3v = fmaxf(acc2 + s_bb[t], 0.f);
    const int kk = 640 + h*128 + t;
    xcatpk[(size_t)(s>>4)*18432 + (kk>>5)*512 + (s&15)*32 + (kk&31)] = packbf(x3v);
  }
}

// heads epilogue for sample ss (uses s_p[24]; needs >=256 active threads of 512/256 block)
__device__ __forceinline__ void hepi_body(
    const float* __restrict__ hpart,
    const float* __restrict__ q_b1, const float* __restrict__ q_w2, const float* __restrict__ q_b2,
    const float* __restrict__ v_b1, const float* __restrict__ v_w2, const float* __restrict__ v_b2,
    float* __restrict__ out, float* s_p, int ss, int t)
{
  const int w = t>>6, lane = t&63;
  if (t < 256){
    float hq = q_b1[t], hv = v_b1[t];
    #pragma unroll
    for (int ks=0; ks<8; ks++){
      hq += hpart[(size_t)ks*65536 + (size_t)ss*512 + t];
      hv += hpart[(size_t)ks*65536 + (size_t)ss*512 + 256 + t];
    }
    hq = fmaxf(hq, 0.f);
    hv = fmaxf(hv, 0.f);
    float p[6];
    #pragma unroll
    for (int o=0;o<5;o++) p[o] = hq * q_w2[t*5+o];
    p[5] = hv * v_w2[t];
    #pragma unroll
    for (int d_=32; d_; d_>>=1){
      #pragma unroll
      for (int o=0;o<6;o++) p[o] += __shfl_xor(p[o], d_, 64);
    }
    if (lane==0){
      #pragma unroll
      for (int o=0;o<6;o++) s_p[w*6+o] = p[o];
    }
  }
  __syncthreads();
  if (t < 6) s_p[t] = s_p[t] + s_p[6+t] + s_p[12+t] + s_p[18+t];
  __syncthreads();
  if (t < 5){
    const float q0 = s_p[0]+q_b2[0], q1 = s_p[1]+q_b2[1], q2 = s_p[2]+q_b2[2],
                q3 = s_p[3]+q_b2[3], q4 = s_p[4]+q_b2[4];
    const float mean = (q0+q1+q2+q3+q4) / 5.0f;
    const float v = s_p[5] + v_b2[0];
    const float qt = (t==0?q0:t==1?q1:t==2?q2:t==3?q3:q4);
    out[ss*5+t] = qt - mean + v;
  }
}

// convert one 32x32 tile job cw
__device__ __forceinline__ void conv_body(
    const float* __restrict__ wl2, const float* __restrict__ q_w1,
    const float* __restrict__ v_w1, const float* __restrict__ wr2,
    ushort_t* __restrict__ wl2Thi, ushort_t* __restrict__ wl2Tlo,
    ushort_t* __restrict__ qw1Thi, ushort_t* __restrict__ qw1Tlo,
    ushort_t* __restrict__ vw1Thi, ushort_t* __restrict__ vw1Tlo,
    ushort_t* __restrict__ wr2Thi, ushort_t* __restrict__ wr2Tlo,
    float* sm, int cw, int t)
{
  const float* in; ushort_t* ohi; ushort_t* olo; int K, N, tt;
  if (cw < 256)      { in=wl2;  ohi=wl2Thi; olo=wl2Tlo; K=512;  N=512; tt=cw; }
  else if (cw < 544) { in=q_w1; ohi=qw1Thi; olo=qw1Tlo; K=1152; N=256; tt=cw-256; }
  else if (cw < 832) { in=v_w1; ohi=vw1Thi; olo=vw1Tlo; K=1152; N=256; tt=cw-544; }
  else               { in=wr2;  ohi=wr2Thi; olo=wr2Tlo; K=512;  N=512; tt=cw-832; }
  const int ktiles = K>>5;
  const int kt = tt % ktiles, nt = tt / ktiles;
  const int r = t>>5, c = t&31;   // r in [0,16)
  #pragma unroll
  for (int i=0;i<2;i++)
    sm[(r+i*16)*33 + c] = in[(size_t)(kt*32 + r + i*16)*N + nt*32 + c];
  __syncthreads();
  #pragma unroll
  for (int i=0;i<2;i++){
    const int nl = r + i*16;
    const int n  = nt*32 + nl;
    const float f = sm[c*33 + nl];
    const unsigned hb = bf16rne(f);
    const float hf = __uint_as_float(hb<<16);
    const unsigned lb = bf16rne(f - hf);
    const size_t off = (size_t)(n>>4)*(16*K) + (size_t)kt*512 + (size_t)(n&15)*32 + c;
    ohi[off] = (ushort_t)hb;
    olo[off] = (ushort_t)lb;
  }
  __syncthreads();
}

// =============== Cooperative mega kernel (512 blocks x 512 threads) ===============
__global__ __launch_bounds__(512, 4) void mega_kernel(
    const uint_t* __restrict__ xpk,
    const ushort_t* __restrict__ wl1Thi, const ushort_t* __restrict__ wl1Tlo,
    const ushort_t* __restrict__ wr1Thi, const ushort_t* __restrict__ wr1Tlo,
    const float* __restrict__ att1, const float* __restrict__ bias1,
    const unsigned* __restrict__ adjw, const int* __restrict__ aiw,
    const float* __restrict__ wl2, const float* __restrict__ q_w1,
    const float* __restrict__ v_w1, const float* __restrict__ wr2,
    ushort_t* __restrict__ wl2Thi, ushort_t* __restrict__ wl2Tlo,
    ushort_t* __restrict__ qw1Thi, ushort_t* __restrict__ qw1Tlo,
    ushort_t* __restrict__ vw1Thi, ushort_t* __restrict__ vw1Tlo,
    ushort_t* __restrict__ wr2Thi, ushort_t* __restrict__ wr2Tlo,
    uint_t* __restrict__ x2pk, uint_t* __restrict__ xcatpk,
    const float* __restrict__ att2, const float* __restrict__ bias2,
    float* __restrict__ GR, float* __restrict__ hpart,
    const float* __restrict__ q_b1, const float* __restrict__ q_w2,
    const float* __restrict__ q_b2, const float* __restrict__ v_b1,
    const float* __restrict__ v_w2, const float* __restrict__ v_b2,
    float* __restrict__ out)
{
  __shared__ __align__(16) float s_gl[32*132];
  __shared__ __align__(16) float s_gr[32*132];
  __shared__ __align__(16) float s_att[128];
  __shared__ __align__(16) float s_b[128];
  __shared__ float s_lg[32*33];
  __shared__ unsigned s_adj[32];
  __shared__ float s_p[24];

  cg::grid_group gg = cg::this_grid();
  const int t = threadIdx.x, bid = blockIdx.x;
  const int s = bid & 127, h = bid >> 7;

  // Phase A.1: converts (1088 jobs over 512 blocks)
  {
    const int njobs = (bid < 64) ? 3 : 2;
    for (int jj=0; jj<njobs; jj++){
      conv_body(wl2, q_w1, v_w1, wr2, wl2Thi, wl2Tlo, qw1Thi, qw1Tlo,
                vw1Thi, vw1Tlo, wr2Thi, wr2Tlo, s_gl, bid + jj*512, t);
    }
  }

  // Phase A.2: GAT1
  gat1_body(xpk, wl1Thi, wl1Tlo, wr1Thi, wr1Tlo, att1, bias1, adjw, aiw,
            x2pk, xcatpk, s_gl, s_gr, s_att, s_b, s_lg, s_adj, s, h, t);

  __threadfence_system();
  gg.sync();
  __threadfence_system();

  // Phase B: GR GEMM + hgemm k<640
  if (bid < 32){
    gr_body(xcatpk, wr2Thi, wr2Tlo, GR, bid, t);
  } else if (bid < 64){
    const int hk = bid - 32;
    hgemm_body<5>(xcatpk, qw1Thi, qw1Tlo, vw1Thi, vw1Tlo, hpart, hk>>3, hk&7, t, 0, 0);
  }

  __threadfence_system();
  gg.sync();
  __threadfence_system();

  // Phase C: GAT2
  gat2_body(x2pk, wl2Thi, wl2Tlo, GR, att2, bias2, adjw, aiw, xcatpk,
            s_gl, s_gr /*p2*/, s_att, s_b, s_lg /*lg32*/, s_lg+64 /*al32*/, s, h, t);

  __threadfence_system();
  gg.sync();
  __threadfence_system();

  // Phase D: hgemm k in [640,1152)
  if (bid < 32){
    hgemm_body<4>(xcatpk, qw1Thi, qw1Tlo, vw1Thi, vw1Tlo, hpart, bid>>3, bid&7, t, 20, 4);
  }

  __threadfence_system();
  gg.sync();
  __threadfence_system();

  // Phase E: heads epilogue
  if (bid < 128){
    hepi_body(hpart, q_b1, q_w2, q_b2, v_b1, v_w2, v_b2, out, s_p, bid, t);
  }
}

// =============== Fallback kernels (verified Round-2 structure) ===============
__global__ __launch_bounds__(512) void pa1_kernel(
    const uint_t* __restrict__ xpk,
    const ushort_t* __restrict__ wl1Thi, const ushort_t* __restrict__ wl1Tlo,
    const ushort_t* __restrict__ wr1Thi, const ushort_t* __restrict__ wr1Tlo,
    const float* __restrict__ att, const float* __restrict__ bias,
    const unsigned* __restrict__ adjw, const int* __restrict__ aiw,
    const float* __restrict__ wl2, const float* __restrict__ q_w1,
    const float* __restrict__ v_w1, const float* __restrict__ wr2,
    ushort_t* __restrict__ wl2Thi, ushort_t* __restrict__ wl2Tlo,
    ushort_t* __restrict__ qw1Thi, ushort_t* __restrict__ qw1Tlo,
    ushort_t* __restrict__ vw1Thi, ushort_t* __restrict__ vw1Tlo,
    ushort_t* __restrict__ wr2Thi, ushort_t* __restrict__ wr2Tlo,
    uint_t* __restrict__ x2pk, uint_t* __restrict__ xcatpk)
{
  __shared__ __align__(16) float s_gl[32*132];
  __shared__ __align__(16) float s_gr[32*132];
  __shared__ __align__(16) float s_att[128];
  __shared__ __align__(16) float s_b[128];
  __shared__ float s_lg[32*33];
  __shared__ unsigned s_adj[32];
  const int t = threadIdx.x, bid = blockIdx.x;
  if (bid >= 512){
    conv_body(wl2, q_w1, v_w1, wr2, wl2Thi, wl2Tlo, qw1Thi, qw1Tlo,
              vw1Thi, vw1Tlo, wr2Thi, wr2Tlo, s_gl, bid - 512, t);
    return;
  }
  const int s = bid & 127, h = bid >> 7;
  gat1_body(xpk, wl1Thi, wl1Tlo, wr1Thi, wr1Tlo, att, bias, adjw, aiw,
            x2pk, xcatpk, s_gl, s_gr, s_att, s_b, s_lg, s_adj, s, h, t);
}

__global__ __launch_bounds__(512) void gr2_kernel(
    const uint_t* __restrict__ xcatpk,
    const ushort_t* __restrict__ wr2Thi, const ushort_t* __restrict__ wr2Tlo,
    const ushort_t* __restrict__ qw1Thi, const ushort_t* __restrict__ qw1Tlo,
    const ushort_t* __restrict__ vw1Thi, const ushort_t* __restrict__ vw1Tlo,
    float* __restrict__ hpart, float* __restrict__ GR)
{
  const int t = threadIdx.x, bid = blockIdx.x;
  if (bid >= 32){
    const int hk = bid - 32;
    hgemm_body<5>(xcatpk, qw1Thi, qw1Tlo, vw1Thi, vw1Tlo, hpart, hk>>3, hk&7, t, 0, 0);
    return;
  }
  gr_body(xcatpk, wr2Thi, wr2Tlo, GR, bid, t);
}

__global__ __launch_bounds__(512) void pa2_kernel(
    const uint_t* __restrict__ x2pk,
    const ushort_t* __restrict__ wl2Thi, const ushort_t* __restrict__ wl2Tlo,
    const float* __restrict__ GR,
    const float* __restrict__ att2, const float* __restrict__ bias2,
    const unsigned* __restrict__ adjw, const int* __restrict__ aiw,
    uint_t* __restrict__ xcatpk)
{
  __shared__ __align__(16) float s_gl[32*132];
  __shared__ __align__(16) float s_p2[128];
  __shared__ __align__(16) float s_at[128];
  __shared__ __align__(16) float s_bb[128];
  __shared__ float s_lg[32];
  __shared__ float s_al[32];
  const int t = threadIdx.x, bid = blockIdx.x;
  const int s = bid & 127, h = bid >> 7;
  gat2_body(x2pk, wl2Thi, wl2Tlo, GR, att2, bias2, adjw, aiw, xcatpk,
            s_gl, s_p2, s_at, s_bb, s_lg, s_al, s, h, t);
}

__global__ __launch_bounds__(512) void x3g_kernel(
    const uint_t* __restrict__ xcatpk,
    const ushort_t* __restrict__ qw1Thi, const ushort_t* __restrict__ qw1Tlo,
    const ushort_t* __restrict__ vw1Thi, const ushort_t* __restrict__ vw1Tlo,
    float* __restrict__ hpart)
{
  const int t = threadIdx.x, bid = blockIdx.x;
  hgemm_body<4>(xcatpk, qw1Thi, qw1Tlo, vw1Thi, vw1Tlo, hpart, bid>>3, bid&7, t, 20, 4);
}

__global__ __launch_bounds__(256) void hepi_kernel(
    const float* __restrict__ hpart,
    const float* __restrict__ q_b1, const float* __restrict__ q_w2, const float* __restrict__ q_b2,
    const float* __restrict__ v_b1, const float* __restrict__ v_w2, const float* __restrict__ v_b2,
    float* __restrict__ out)
{
  __shared__ float s_p[24];
  hepi_body(hpart, q_b1, q_w2, q_b2, v_b1, v_w2, v_b2, out, s_p, blockIdx.x, threadIdx.x);
}

extern "C" void kernel_launch(void* const* d_in, const int* in_sizes, int n_in,
                              void* d_out, int out_size, void* d_ws, size_t ws_size,
                              hipStream_t stream) {
  (void)n_in; (void)out_size; (void)ws_size;
  const float* obs    = (const float*)d_in[0];
  const float* enc_w1 = (const float*)d_in[1];
  const float* enc_b1 = (const float*)d_in[2];
  const float* enc_w2 = (const float*)d_in[3];
  const float* enc_b2 = (const float*)d_in[4];
  const float* wl1    = (const float*)d_in[5];
  const float* wr1    = (const float*)d_in[6];
  const float* att1   = (const float*)d_in[7];
  const float* bias1  = (const float*)d_in[8];
  const float* wl2    = (const float*)d_in[9];
  const float* wr2    = (const float*)d_in[10];
  const float* att2   = (const float*)d_in[11];
  const float* bias2  = (const float*)d_in[12];
  const float* q_w1   = (const float*)d_in[13];
  const float* q_b1   = (const float*)d_in[14];
  const float* q_w2   = (const float*)d_in[15];
  const float* q_b2   = (const float*)d_in[16];
  const float* v_w1   = (const float*)d_in[17];
  const float* v_b1   = (const float*)d_in[18];
  const float* v_w2   = (const float*)d_in[19];
  const float* v_b2   = (const float*)d_in[20];

  // Workspace layout — no aliasing (ws_size is ~268 MB per harness fill; we use 18.4 MB).
  char* ws = (char*)d_ws;
  uint_t*   x_pk    = (uint_t*)  (ws + 0);           // 2,097,152
  uint_t*   xcat_pk = (uint_t*)  (ws + 2097152);     //   589,824
  unsigned* adjw    = (unsigned*)(ws + 2686976);     //    16,384
  int*      aiw     = (int*)     (ws + 2703360);     //       512
  uint_t*   x2_pk   = (uint_t*)  (ws + 2703872);     // 8,388,608
  ushort_t* wl1Thi  = (ushort_t*)(ws + 11092480);    //   131,072
  ushort_t* wl1Tlo  = (ushort_t*)(ws + 11223552);    //   131,072
  ushort_t* wr1Thi  = (ushort_t*)(ws + 11354624);    //   131,072
  ushort_t* wr1Tlo  = (ushort_t*)(ws + 11485696);    //   131,072
  ushort_t* wl2Thi  = (ushort_t*)(ws + 11616768);    //   524,288
  ushort_t* wl2Tlo  = (ushort_t*)(ws + 12141056);    //   524,288
  ushort_t* qw1Thi  = (ushort_t*)(ws + 12665344);    //   589,824
  ushort_t* qw1Tlo  = (ushort_t*)(ws + 13255168);    //   589,824
  ushort_t* vw1Thi  = (ushort_t*)(ws + 13844992);    //   589,824
  ushort_t* vw1Tlo  = (ushort_t*)(ws + 14434816);    //   589,824
  ushort_t* wr2Thi  = (ushort_t*)(ws + 15024640);    //   524,288
  ushort_t* wr2Tlo  = (ushort_t*)(ws + 15548928);    //   524,288
  float*    GR      = (float*)   (ws + 16073216);    //   262,144
  float*    hpart   = (float*)   (ws + 16335360);    // 2,097,152 (ends 18,432,512)

  float* outp = (float*)d_out;

  prep_kernel<<<512 + 128, 256, 0, stream>>>(obs, enc_w1, enc_b1, enc_w2, enc_b2,
      wl1, wr1, wl1Thi, wl1Tlo, wr1Thi, wr1Tlo,
      x_pk, xcat_pk, adjw, aiw);

  void* args[] = {
    (void*)&x_pk,
    (void*)&wl1Thi, (void*)&wl1Tlo,
    (void*)&wr1Thi, (void*)&wr1Tlo,
    (void*)&att1, (void*)&bias1,
    (void*)&adjw, (void*)&aiw,
    (void*)&wl2, (void*)&q_w1,
    (void*)&v_w1, (void*)&wr2,
    (void*)&wl2Thi, (void*)&wl2Tlo,
    (void*)&qw1Thi, (void*)&qw1Tlo,
    (void*)&vw1Thi, (void*)&vw1Tlo,
    (void*)&wr2Thi, (void*)&wr2Tlo,
    (void*)&x2_pk, (void*)&xcat_pk,
    (void*)&att2, (void*)&bias2,
    (void*)&GR, (void*)&hpart,
    (void*)&q_b1, (void*)&q_w2,
    (void*)&q_b2, (void*)&v_b1,
    (void*)&v_w2, (void*)&v_b2,
    (void*)&outp
  };
  hipError_t cerr = hipLaunchCooperativeKernel((void*)mega_kernel, dim3(512), dim3(512),
                                               args, 0, stream);
  if (cerr != hipSuccess){
    // Fallback: verified multi-kernel sequence (Round-2 structure).
    pa1_kernel<<<512 + 1088, 512, 0, stream>>>(x_pk, wl1Thi, wl1Tlo, wr1Thi, wr1Tlo,
        att1, bias1, adjw, aiw,
        wl2, q_w1, v_w1, wr2,
        wl2Thi, wl2Tlo, qw1Thi, qw1Tlo, vw1Thi, vw1Tlo, wr2Thi, wr2Tlo,
        x2_pk, xcat_pk);
    gr2_kernel<<<64, 512, 0, stream>>>(xcat_pk, wr2Thi, wr2Tlo,
        qw1Thi, qw1Tlo, vw1Thi, vw1Tlo, hpart, GR);
    pa2_kernel<<<512, 512, 0, stream>>>(x2_pk, wl2Thi, wl2Tlo, GR,
        att2, bias2, adjw, aiw, xcat_pk);
    x3g_kernel<<<32, 512, 0, stream>>>(xcat_pk, qw1Thi, qw1Tlo, vw1Thi, vw1Tlo, hpart);
    hepi_kernel<<<128, 256, 0, stream>>>(hpart, q_b1, q_w2, q_b2, v_b1, v_w2, v_b2, outp);
  }
}

// Round 5
// 275.129 us; speedup vs baseline: 3.5143x; 3.5143x over previous
//
#include <hip/hip_runtime.h>
#include <hip/hip_bf16.h>

typedef unsigned int uint_t;
typedef unsigned short ushort_t;
typedef __attribute__((ext_vector_type(8))) short short8;
typedef __attribute__((ext_vector_type(4))) float floatx4;

__device__ __forceinline__ float4 fma4(float4 a, float s, float4 w){
  a.x += s*w.x; a.y += s*w.y; a.z += s*w.z; a.w += s*w.w; return a;
}
__device__ __forceinline__ float4 relu4(float4 a){
  return make_float4(fmaxf(a.x,0.f),fmaxf(a.y,0.f),fmaxf(a.z,0.f),fmaxf(a.w,0.f));
}
__device__ __forceinline__ unsigned bf16rne(float f){
  unsigned u = __float_as_uint(f);
  return (u + 0x7fffu + ((u>>16)&1u)) >> 16;
}
__device__ __forceinline__ uint_t packbf(float f){
  unsigned hb = bf16rne(f);
  float hf = __uint_as_float(hb<<16);
  unsigned lb = bf16rne(f - hf);
  return (hb<<16) | lb;
}
__device__ __forceinline__ uint4 pack4(float4 v){
  uint4 u; u.x=packbf(v.x); u.y=packbf(v.y); u.z=packbf(v.z); u.w=packbf(v.w); return u;
}
__device__ __forceinline__ float unpk(uint_t u){
  return __uint_as_float(u & 0xffff0000u) + __uint_as_float(u<<16);
}
#define UNPACK8(u0,u1,hi,lo) \
  hi[0]=(short)(u0.x>>16); lo[0]=(short)u0.x; \
  hi[1]=(short)(u0.y>>16); lo[1]=(short)u0.y; \
  hi[2]=(short)(u0.z>>16); lo[2]=(short)u0.z; \
  hi[3]=(short)(u0.w>>16); lo[3]=(short)u0.w; \
  hi[4]=(short)(u1.x>>16); lo[4]=(short)u1.x; \
  hi[5]=(short)(u1.y>>16); lo[5]=(short)u1.y; \
  hi[6]=(short)(u1.z>>16); lo[6]=(short)u1.z; \
  hi[7]=(short)(u1.w>>16); lo[7]=(short)u1.w;

// Fragment-order offset: off(n,k) = (n>>4)*16*K + (k>>5)*512 + (n&15)*32 + (k&31)

// =============== K1: enc (blocks 0..511, XCD-swizzled) + wl1/wr1 convert (512..639) ===============
__global__ __launch_bounds__(256) void prep_kernel(
    const float* __restrict__ obs,
    const float* __restrict__ enc_w1, const float* __restrict__ enc_b1,
    const float* __restrict__ enc_w2, const float* __restrict__ enc_b2,
    const float* __restrict__ wl1, const float* __restrict__ wr1,
    ushort_t* __restrict__ wl1Thi, ushort_t* __restrict__ wl1Tlo,
    ushort_t* __restrict__ wr1Thi, ushort_t* __restrict__ wr1Tlo,
    uint_t* __restrict__ xpk,
    unsigned* __restrict__ adjw, int* __restrict__ aiw)
{
  const int t = threadIdx.x, bid = blockIdx.x;
  if (bid >= 512){
    __shared__ float sm[32][33];
    const int cw = bid - 512;
    const float* in; ushort_t* ohi; ushort_t* olo; int tt;
    const int K = 128, N = 512;
    if (cw < 64){ in=wl1; ohi=wl1Thi; olo=wl1Tlo; tt=cw; }
    else        { in=wr1; ohi=wr1Thi; olo=wr1Tlo; tt=cw-64; }
    const int ktiles = K>>5;
    const int kt = tt % ktiles, nt = tt / ktiles;
    const int r = t>>5, c = t&31;
    #pragma unroll
    for (int i=0;i<4;i++)
      sm[r+i*8][c] = in[(size_t)(kt*32 + r + i*8)*N + nt*32 + c];
    __syncthreads();
    #pragma unroll
    for (int i=0;i<4;i++){
      const int nl = r + i*8;
      const int n  = nt*32 + nl;
      const float f = sm[c][nl];
      const unsigned hb = bf16rne(f);
      const float hf = __uint_as_float(hb<<16);
      const unsigned lb = bf16rne(f - hf);
      const size_t off = (size_t)(n>>4)*(16*K) + (size_t)kt*512 + (size_t)(n&15)*32 + c;
      ohi[off] = (ushort_t)hb;
      olo[off] = (ushort_t)lb;
    }
    return;
  }
  __shared__ float s_pos[64];
  __shared__ float s_feats[128];
  __shared__ __align__(16) float s_h[8*132];
  __shared__ int s_ai;
  // XCD swizzle: same-sample blocks 128 apart -> same XCD (bid%8 preserved)
  const int s = bid & 127, g = bid >> 7;
  const float* ob = obs + s*577;

  if (t==0){
    float a = ob[576];
    a = fminf(fmaxf(a, 0.f), 31.f);
    s_ai = (int)a;
    if (g==0) aiw[s] = (int)a;
  }
  if (t < 128){ const int n=t>>4, f=t&15; s_feats[t] = ob[(g*8+n)*18+2+f]; }
  if (g==0 && t>=128 && t<192){ const int u=t-128; s_pos[u] = ob[(u>>1)*18 + (u&1)]; }
  __syncthreads();

  if (g==0 && t < 32){
    const float px = s_pos[2*t], py = s_pos[2*t+1];
    const float R2 = 0.09f;
    unsigned mm = 0u;
    for (int j=0;j<32;j++){
      const float dx = __fsub_rn(px, s_pos[2*j]), dy = __fsub_rn(py, s_pos[2*j+1]);
      const float d2 = __fadd_rn(__fmul_rn(dx,dx), __fmul_rn(dy,dy));
      if (d2 <= R2 || j==t) mm |= (1u<<j);
    }
    adjw[s*32+t] = mm;
  }

  const int n = t>>5, c0 = (t&31)*4;
  {
    float4 a = *(const float4*)(enc_b1+c0);
    #pragma unroll
    for (int f=0; f<16; f++)
      a = fma4(a, s_feats[n*16+f], *(const float4*)(enc_w1 + f*128 + c0));
    *(float4*)&s_h[n*132+c0] = relu4(a);
  }
  __syncthreads();
  {
    float4 a = *(const float4*)(enc_b2+c0);
    for (int k=0;k<128;k+=4){
      const float4 hv = *(const float4*)&s_h[n*132+k];
      a = fma4(a, hv.x, *(const float4*)(enc_w2 + (k+0)*128 + c0));
      a = fma4(a, hv.y, *(const float4*)(enc_w2 + (k+1)*128 + c0));
      a = fma4(a, hv.z, *(const float4*)(enc_w2 + (k+2)*128 + c0));
      a = fma4(a, hv.w, *(const float4*)(enc_w2 + (k+3)*128 + c0));
    }
    a = relu4(a);
    const uint4 p = pack4(a);
    const int i = g*8 + n;
    uint_t* xp = xpk + (size_t)(s*2 + (i>>4))*2048 + (c0>>5)*512 + (i&15)*32 + (c0&31);
    *(uint4*)xp = p;
  }
}

// =============== K2: pa1 (blocks 0..511, XCD-swizzled) + wl2 converts (512..767) ===============
// Full-K-per-wave structure (verified Round 2). No agent tap (tail reads x2pk directly).
__global__ __launch_bounds__(512) void pa1_kernel(
    const uint_t* __restrict__ xpk,
    const ushort_t* __restrict__ wl1Thi, const ushort_t* __restrict__ wl1Tlo,
    const ushort_t* __restrict__ wr1Thi, const ushort_t* __restrict__ wr1Tlo,
    const float* __restrict__ att, const float* __restrict__ bias,
    const unsigned* __restrict__ adjw,
    const float* __restrict__ wl2,
    ushort_t* __restrict__ wl2Thi, ushort_t* __restrict__ wl2Tlo,
    uint_t* __restrict__ x2pk)
{
  __shared__ __align__(16) float s_gl[32*132];
  __shared__ __align__(16) float s_gr[32*132];
  __shared__ __align__(16) float s_att[128];
  __shared__ __align__(16) float s_b[128];
  __shared__ float s_lg[32*33];
  __shared__ unsigned s_adj[32];
  const int t = threadIdx.x, bid = blockIdx.x;

  if (bid >= 512){
    // wl2 convert: 256 tile jobs (K=512, N=512)
    const int tt = bid - 512;
    const int kt = tt & 15, nt = tt >> 4;
    const int r = t>>5, c = t&31;
    #pragma unroll
    for (int i=0;i<2;i++)
      s_gl[(r+i*16)*33 + c] = wl2[(size_t)(kt*32 + r + i*16)*512 + nt*32 + c];
    __syncthreads();
    #pragma unroll
    for (int i=0;i<2;i++){
      const int nl = r + i*16;
      const int n  = nt*32 + nl;
      const float f = s_gl[c*33 + nl];
      const unsigned hb = bf16rne(f);
      const float hf = __uint_as_float(hb<<16);
      const unsigned lb = bf16rne(f - hf);
      const size_t off = (size_t)(n>>4)*8192 + (size_t)kt*512 + (size_t)(n&15)*32 + c;
      wl2Thi[off] = (ushort_t)hb;
      wl2Tlo[off] = (ushort_t)lb;
    }
    return;
  }

  // XCD swizzle: same-sample blocks 128 apart -> same XCD
  const int s = bid & 127, h = bid >> 7;
  const int w = t>>6, lane = t&63, m = lane&15, quad = lane>>4;
  const int mat = w>>2, cpair = w&3;   // mat: 0=gl(wl1), 1=gr(wr1); cpair: 32-col chunk

  if (t < 128){ s_att[t] = att[h*128 + t]; s_b[t] = bias[h*128 + t]; }
  if (t >= 224 && t < 256) s_adj[t-224] = adjw[s*32 + (t-224)];

  const ushort_t* Bhi = (mat==0) ? wl1Thi : wr1Thi;
  const ushort_t* Blo = (mat==0) ? wl1Tlo : wr1Tlo;
  const int nbase = h*8 + cpair*2;
  const uint_t* a0p = xpk + (size_t)(s*2+0)*2048 + m*32 + quad*8;
  const uint_t* a1p = xpk + (size_t)(s*2+1)*2048 + m*32 + quad*8;
  const ushort_t* bp0 = Bhi + (size_t)(nbase+0)*2048 + m*32 + quad*8;
  const ushort_t* bp1 = Bhi + (size_t)(nbase+1)*2048 + m*32 + quad*8;
  const size_t lod = (size_t)(Blo - Bhi);
  floatx4 acc[2][2];
  #pragma unroll
  for (int i=0;i<2;i++)
    #pragma unroll
    for (int j=0;j<2;j++) acc[i][j] = (floatx4){0.f,0.f,0.f,0.f};

  #pragma unroll
  for (int kc=0; kc<4; kc++){
    const uint4 u00 = *(const uint4*)(a0p + kc*512);
    const uint4 u01 = *(const uint4*)(a0p + kc*512 + 4);
    const uint4 u10 = *(const uint4*)(a1p + kc*512);
    const uint4 u11 = *(const uint4*)(a1p + kc*512 + 4);
    short8 ahi0, alo0, ahi1, alo1;
    UNPACK8(u00,u01,ahi0,alo0)
    UNPACK8(u10,u11,ahi1,alo1)
    const ushort_t* bps[2] = {bp0, bp1};
    #pragma unroll
    for (int nt=0; nt<2; nt++){
      const short8 bh = *(const short8*)(bps[nt] + kc*512);
      const short8 bl = *(const short8*)(bps[nt] + kc*512 + lod);
      acc[0][nt] = __builtin_amdgcn_mfma_f32_16x16x32_bf16(ahi0, bh, acc[0][nt], 0,0,0);
      acc[0][nt] = __builtin_amdgcn_mfma_f32_16x16x32_bf16(ahi0, bl, acc[0][nt], 0,0,0);
      acc[0][nt] = __builtin_amdgcn_mfma_f32_16x16x32_bf16(alo0, bh, acc[0][nt], 0,0,0);
      acc[1][nt] = __builtin_amdgcn_mfma_f32_16x16x32_bf16(ahi1, bh, acc[1][nt], 0,0,0);
      acc[1][nt] = __builtin_amdgcn_mfma_f32_16x16x32_bf16(ahi1, bl, acc[1][nt], 0,0,0);
      acc[1][nt] = __builtin_amdgcn_mfma_f32_16x16x32_bf16(alo1, bh, acc[1][nt], 0,0,0);
    }
  }
  {
    float* dst = mat ? s_gr : s_gl;
    const int colbase = cpair*32;
    #pragma unroll
    for (int nt=0; nt<2; nt++){
      const int col = colbase + nt*16 + m;
      #pragma unroll
      for (int r=0;r<4;r++){
        dst[(quad*4+r)*132 + col]      = acc[0][nt][r];
        dst[(16+quad*4+r)*132 + col]   = acc[1][nt][r];
      }
    }
  }
  __syncthreads();

  // logits
  {
    const int i = t>>4, jb = t&15;
    float lacc[2] = {0.f,0.f};
    for (int c=0;c<128;c+=4){
      const float4 g = *(const float4*)&s_gr[i*132+c];
      const float4 a = *(const float4*)&s_att[c];
      #pragma unroll
      for (int mm=0;mm<2;mm++){
        const float4 gj = *(const float4*)&s_gl[(jb+16*mm)*132 + c];
        float ex = g.x+gj.x; ex = fmaxf(ex, 0.2f*ex);
        float ey = g.y+gj.y; ey = fmaxf(ey, 0.2f*ey);
        float ez = g.z+gj.z; ez = fmaxf(ez, 0.2f*ez);
        float ew = g.w+gj.w; ew = fmaxf(ew, 0.2f*ew);
        lacc[mm] += ex*a.x + ey*a.y + ez*a.z + ew*a.w;
      }
    }
    s_lg[i*33 + jb]      = lacc[0];
    s_lg[i*33 + jb + 16] = lacc[1];
  }
  __syncthreads();

  // masked softmax
  #pragma unroll
  for (int rnd=0; rnd<2; rnd++){
    const int i = rnd*16 + (t>>5), j = t&31;
    const float lg = s_lg[i*33+j];
    const bool ok = (s_adj[i]>>j)&1u;
    float v = ok ? lg : -3.0e38f;
    #pragma unroll
    for (int d_=16; d_; d_>>=1) v = fmaxf(v, __shfl_xor(v, d_, 32));
    const float e = ok ? __expf(lg - v) : 0.f;
    float sum = e;
    #pragma unroll
    for (int d_=16; d_; d_>>=1) sum += __shfl_xor(sum, d_, 32);
    s_lg[i*33+j] = e / sum;
  }
  __syncthreads();

  // aggregate -> packed x2
  {
    const int i = t>>4, c0 = (t&15)*8;
    float4 o0 = make_float4(0.f,0.f,0.f,0.f), o1 = o0;
    for (int j=0;j<32;j++){
      const float al = s_lg[i*33+j];
      o0 = fma4(o0, al, *(const float4*)&s_gl[j*132 + c0]);
      o1 = fma4(o1, al, *(const float4*)&s_gl[j*132 + c0 + 4]);
    }
    const float4 b0 = *(const float4*)&s_b[c0];
    const float4 b1 = *(const float4*)&s_b[c0+4];
    o0 = relu4(make_float4(o0.x+b0.x, o0.y+b0.y, o0.z+b0.z, o0.w+b0.w));
    o1 = relu4(make_float4(o1.x+b1.x, o1.y+b1.y, o1.z+b1.z, o1.w+b1.w));
    const uint4 p0 = pack4(o0), p1 = pack4(o1);
    const int kb = h*128 + c0;
    uint_t* xp = x2pk + (size_t)(s*2 + (i>>4))*8192 + (kb>>5)*512 + (i&15)*32 + (kb&31);
    *(uint4*)&xp[0] = p0;
    *(uint4*)&xp[4] = p1;
  }
}

// =============== K3: per-sample tail (128 blocks x 512 threads) ===============
// Per sample: x1/x2_agent load -> GR GEMV -> 4x {gl2 MFMA, logits, softmax, aggregate -> x3}
// -> heads GEMV (K=1152) -> dueling combine -> out. No cross-block deps.
__global__ __launch_bounds__(512) void tail_kernel(
    const uint_t* __restrict__ xpk, const uint_t* __restrict__ x2pk,
    const ushort_t* __restrict__ wl2Thi, const ushort_t* __restrict__ wl2Tlo,
    const float* __restrict__ wr2,
    const float* __restrict__ att2, const float* __restrict__ bias2,
    const unsigned* __restrict__ adjw, const int* __restrict__ aiw,
    const float* __restrict__ q_w1, const float* __restrict__ q_b1,
    const float* __restrict__ q_w2, const float* __restrict__ q_b2,
    const float* __restrict__ v_w1, const float* __restrict__ v_b1,
    const float* __restrict__ v_w2, const float* __restrict__ v_b2,
    float* __restrict__ out)
{
  __shared__ __align__(16) float s_gl[32*132];
  __shared__ __align__(16) float s_xc[1152];   // xcat: x1 | x2_agent | x3
  __shared__ __align__(16) float s_p2[512];    // GR row (all 4 head slices)
  __shared__ __align__(16) float s_at[128];
  __shared__ __align__(16) float s_bb[128];
  __shared__ float s_lg[32];
  __shared__ float s_al[32];
  __shared__ float s_p6[8*6];
  const int t = threadIdx.x, s = blockIdx.x;
  const int w = t>>6, lane = t&63, m = lane&15, quad = lane>>4;
  const int ai = aiw[s];
  const unsigned arow = adjw[s*32+ai];

  // load x1 (agent row of x) and x2_agent
  if (t < 128)
    s_xc[t] = unpk(xpk[(size_t)(s*2 + (ai>>4))*2048 + (t>>5)*512 + (ai&15)*32 + (t&31)]);
  s_xc[128+t] = unpk(x2pk[(size_t)(s*2 + (ai>>4))*8192 + (t>>5)*512 + (ai&15)*32 + (t&31)]);
  __syncthreads();

  // GR GEMV: s_p2[c] = sum_k x2a[k] * wr2[k,c]  (coalesced across threads)
  {
    float acc = 0.f;
    #pragma unroll 8
    for (int k=0;k<512;k++) acc += s_xc[128+k] * wr2[(size_t)k*512 + t];
    s_p2[t] = acc;
  }

  // GAT2 per head
  const size_t lod = (size_t)(wl2Tlo - wl2Thi);
  for (int h=0; h<4; h++){
    // gl2 slice: 32 nodes x 128 cols, K=512 (MFMA; wave w = 16-col tile)
    const uint_t* a0p = x2pk + (size_t)(s*2+0)*8192 + m*32 + quad*8;
    const uint_t* a1p = x2pk + (size_t)(s*2+1)*8192 + m*32 + quad*8;
    const ushort_t* bq = wl2Thi + (size_t)(h*8 + w)*8192 + m*32 + quad*8;
    floatx4 acc0 = (floatx4){0.f,0.f,0.f,0.f}, acc1 = acc0;
    #pragma unroll 4
    for (int kc=0; kc<16; kc++){
      const uint4 u00 = *(const uint4*)(a0p + kc*512);
      const uint4 u01 = *(const uint4*)(a0p + kc*512 + 4);
      const uint4 u10 = *(const uint4*)(a1p + kc*512);
      const uint4 u11 = *(const uint4*)(a1p + kc*512 + 4);
      short8 ahi0, alo0, ahi1, alo1;
      UNPACK8(u00,u01,ahi0,alo0)
      UNPACK8(u10,u11,ahi1,alo1)
      const short8 bh = *(const short8*)(bq + kc*512);
      const short8 bl = *(const short8*)(bq + kc*512 + lod);
      acc0 = __builtin_amdgcn_mfma_f32_16x16x32_bf16(ahi0, bh, acc0, 0,0,0);
      acc0 = __builtin_amdgcn_mfma_f32_16x16x32_bf16(ahi0, bl, acc0, 0,0,0);
      acc0 = __builtin_amdgcn_mfma_f32_16x16x32_bf16(alo0, bh, acc0, 0,0,0);
      acc1 = __builtin_amdgcn_mfma_f32_16x16x32_bf16(ahi1, bh, acc1, 0,0,0);
      acc1 = __builtin_amdgcn_mfma_f32_16x16x32_bf16(ahi1, bl, acc1, 0,0,0);
      acc1 = __builtin_amdgcn_mfma_f32_16x16x32_bf16(alo1, bh, acc1, 0,0,0);
    }
    if (t < 128){ s_at[t] = att2[h*128+t]; s_bb[t] = bias2[h*128+t]; }
    {
      const int col = w*16 + m;
      #pragma unroll
      for (int r=0;r<4;r++){
        s_gl[(quad*4+r)*132 + col]    = acc0[r];
        s_gl[(16+quad*4+r)*132 + col] = acc1[r];
      }
    }
    __syncthreads();

    // logits
    if (t < 256){
      const int j = t>>3, pq = t&7;
      float sum = 0.f;
      #pragma unroll
      for (int q=0;q<4;q++){
        const int c = pq*16 + q*4;
        const float4 g = *(const float4*)&s_gl[j*132 + c];
        const float4 r = *(const float4*)&s_p2[h*128 + c];
        const float4 a = *(const float4*)&s_at[c];
        float e0 = r.x+g.x; e0 = fmaxf(e0, 0.2f*e0);
        float e1 = r.y+g.y; e1 = fmaxf(e1, 0.2f*e1);
        float e2 = r.z+g.z; e2 = fmaxf(e2, 0.2f*e2);
        float e3 = r.w+g.w; e3 = fmaxf(e3, 0.2f*e3);
        sum += e0*a.x + e1*a.y + e2*a.z + e3*a.w;
      }
      sum += __shfl_xor(sum,1,64);
      sum += __shfl_xor(sum,2,64);
      sum += __shfl_xor(sum,4,64);
      if (pq==0) s_lg[j] = sum;
    }
    __syncthreads();
    if (t < 32){
      const float lg = s_lg[t];
      const bool ok = (arow>>t)&1u;
      float v = ok ? lg : -3.0e38f;
      #pragma unroll
      for (int d_=16; d_; d_>>=1) v = fmaxf(v, __shfl_xor(v, d_, 32));
      const float e = ok ? __expf(lg - v) : 0.f;
      float sm = e;
      #pragma unroll
      for (int d_=16; d_; d_>>=1) sm += __shfl_xor(sm, d_, 32);
      s_al[t] = e / sm;
    }
    __syncthreads();
    if (t < 128){
      float acc2 = 0.f;
      #pragma unroll 8
      for (int j=0;j<32;j++) acc2 += s_al[j] * s_gl[j*132 + t];
      s_xc[640 + h*128 + t] = fmaxf(acc2 + s_bb[t], 0.f);
    }
    __syncthreads();   // protect s_gl/s_at/s_bb for next h, and x3 before heads
  }

  // heads layer 1: t<256 -> q col t; t>=256 -> v col (t-256). K=1152 from LDS.
  float val;
  {
    const float* W = (t<256) ? q_w1 : v_w1;
    const float* B = (t<256) ? q_b1 : v_b1;
    const int col = t & 255;
    float acc = 0.f;
    #pragma unroll 8
    for (int k=0;k<1152;k++) acc += s_xc[k] * W[(size_t)k*256 + col];
    val = fmaxf(acc + B[col], 0.f);
  }

  // final dueling combine
  float p[6];
  #pragma unroll
  for (int o=0;o<6;o++) p[o] = 0.f;
  if (t < 256){
    #pragma unroll
    for (int o=0;o<5;o++) p[o] = val * q_w2[t*5+o];
  } else {
    p[5] = val * v_w2[t-256];
  }
  #pragma unroll
  for (int d_=32; d_; d_>>=1){
    #pragma unroll
    for (int o=0;o<6;o++) p[o] += __shfl_xor(p[o], d_, 64);
  }
  if (lane==0){
    #pragma unroll
    for (int o=0;o<6;o++) s_p6[w*6+o] = p[o];
  }
  __syncthreads();
  if (t < 6){
    float v = 0.f;
    #pragma unroll
    for (int ww=0; ww<8; ww++) v += s_p6[ww*6 + t];
    s_p6[t] = v;
  }
  __syncthreads();
  if (t < 5){
    const float q0 = s_p6[0]+q_b2[0], q1 = s_p6[1]+q_b2[1], q2 = s_p6[2]+q_b2[2],
                q3 = s_p6[3]+q_b2[3], q4 = s_p6[4]+q_b2[4];
    const float mean = (q0+q1+q2+q3+q4) / 5.0f;
    const float v = s_p6[5] + v_b2[0];
    const float qt = (t==0?q0:t==1?q1:t==2?q2:t==3?q3:q4);
    out[s*5+t] = qt - mean + v;
  }
}

extern "C" void kernel_launch(void* const* d_in, const int* in_sizes, int n_in,
                              void* d_out, int out_size, void* d_ws, size_t ws_size,
                              hipStream_t stream) {
  (void)n_in; (void)out_size; (void)ws_size;
  const float* obs    = (const float*)d_in[0];
  const float* enc_w1 = (const float*)d_in[1];
  const float* enc_b1 = (const float*)d_in[2];
  const float* enc_w2 = (const float*)d_in[3];
  const float* enc_b2 = (const float*)d_in[4];
  const float* wl1    = (const float*)d_in[5];
  const float* wr1    = (const float*)d_in[6];
  const float* att1   = (const float*)d_in[7];
  const float* bias1  = (const float*)d_in[8];
  const float* wl2    = (const float*)d_in[9];
  const float* wr2    = (const float*)d_in[10];
  const float* att2   = (const float*)d_in[11];
  const float* bias2  = (const float*)d_in[12];
  const float* q_w1   = (const float*)d_in[13];
  const float* q_b1   = (const float*)d_in[14];
  const float* q_w2   = (const float*)d_in[15];
  const float* q_b2   = (const float*)d_in[16];
  const float* v_w1   = (const float*)d_in[17];
  const float* v_b1   = (const float*)d_in[18];
  const float* v_w2   = (const float*)d_in[19];
  const float* v_b2   = (const float*)d_in[20];

  // Workspace layout (total ~12.1 MB, no aliasing):
  char* ws = (char*)d_ws;
  uint_t*   x_pk    = (uint_t*)  (ws + 0);           // 2,097,152
  unsigned* adjw    = (unsigned*)(ws + 2097152);     //    16,384
  int*      aiw     = (int*)     (ws + 2113536);     //       512
  uint_t*   x2_pk   = (uint_t*)  (ws + 2114048);     // 8,388,608
  ushort_t* wl1Thi  = (ushort_t*)(ws + 10502656);    //   131,072
  ushort_t* wl1Tlo  = (ushort_t*)(ws + 10633728);    //   131,072
  ushort_t* wr1Thi  = (ushort_t*)(ws + 10764800);    //   131,072
  ushort_t* wr1Tlo  = (ushort_t*)(ws + 10895872);    //   131,072
  ushort_t* wl2Thi  = (ushort_t*)(ws + 11026944);    //   524,288
  ushort_t* wl2Tlo  = (ushort_t*)(ws + 11551232);    //   524,288 (ends 12,075,520)

  prep_kernel<<<512 + 128, 256, 0, stream>>>(obs, enc_w1, enc_b1, enc_w2, enc_b2,
      wl1, wr1, wl1Thi, wl1Tlo, wr1Thi, wr1Tlo,
      x_pk, adjw, aiw);

  pa1_kernel<<<512 + 256, 512, 0, stream>>>(x_pk, wl1Thi, wl1Tlo, wr1Thi, wr1Tlo,
      att1, bias1, adjw,
      wl2, wl2Thi, wl2Tlo, x2_pk);

  tail_kernel<<<128, 512, 0, stream>>>(x_pk, x2_pk, wl2Thi, wl2Tlo, wr2,
      att2, bias2, adjw, aiw,
      q_w1, q_b1, q_w2, q_b2, v_w1, v_b1, v_w2, v_b2,
      (float*)d_out);
}

// Round 6
// 207.235 us; speedup vs baseline: 4.6656x; 1.3276x over previous
//
#include <hip/hip_runtime.h>
#include <hip/hip_bf16.h>

typedef unsigned int uint_t;
typedef unsigned short ushort_t;
typedef __attribute__((ext_vector_type(8))) short short8;
typedef __attribute__((ext_vector_type(4))) float floatx4;

__device__ __forceinline__ float4 fma4(float4 a, float s, float4 w){
  a.x += s*w.x; a.y += s*w.y; a.z += s*w.z; a.w += s*w.w; return a;
}
__device__ __forceinline__ float4 relu4(float4 a){
  return make_float4(fmaxf(a.x,0.f),fmaxf(a.y,0.f),fmaxf(a.z,0.f),fmaxf(a.w,0.f));
}
__device__ __forceinline__ unsigned bf16rne(float f){
  unsigned u = __float_as_uint(f);
  return (u + 0x7fffu + ((u>>16)&1u)) >> 16;
}
__device__ __forceinline__ uint_t packbf(float f){
  unsigned hb = bf16rne(f);
  float hf = __uint_as_float(hb<<16);
  unsigned lb = bf16rne(f - hf);
  return (hb<<16) | lb;
}
__device__ __forceinline__ uint4 pack4(float4 v){
  uint4 u; u.x=packbf(v.x); u.y=packbf(v.y); u.z=packbf(v.z); u.w=packbf(v.w); return u;
}
__device__ __forceinline__ float unpk(uint_t u){
  return __uint_as_float(u & 0xffff0000u) + __uint_as_float(u<<16);
}
#define UNPACK8(u0,u1,hi,lo) \
  hi[0]=(short)(u0.x>>16); lo[0]=(short)u0.x; \
  hi[1]=(short)(u0.y>>16); lo[1]=(short)u0.y; \
  hi[2]=(short)(u0.z>>16); lo[2]=(short)u0.z; \
  hi[3]=(short)(u0.w>>16); lo[3]=(short)u0.w; \
  hi[4]=(short)(u1.x>>16); lo[4]=(short)u1.x; \
  hi[5]=(short)(u1.y>>16); lo[5]=(short)u1.y; \
  hi[6]=(short)(u1.z>>16); lo[6]=(short)u1.z; \
  hi[7]=(short)(u1.w>>16); lo[7]=(short)u1.w;

// Fragment-order offset: off(n,k) = (n>>4)*16*K + (k>>5)*512 + (n&15)*32 + (k&31)

// heads GEMM K-window body: job (ks, ct in 0..7), 512 threads (8 waves = 8 row-blocks).
// Covers K tiles [k0c + ks*NKC, +NKC). Writes partial slot (slot0+ks).
template<int NKC>
__device__ __forceinline__ void hgemm_body(
    const uint_t* __restrict__ xcatpk,
    const ushort_t* __restrict__ qw1Thi, const ushort_t* __restrict__ qw1Tlo,
    const ushort_t* __restrict__ vw1Thi, const ushort_t* __restrict__ vw1Tlo,
    float* __restrict__ part, int ks, int ct, int t, int k0c, int slot0)
{
  const int w = t>>6, lane = t&63, m = lane&15, quad = lane>>4;
  const ushort_t* Bhi = (ct<4) ? qw1Thi : vw1Thi;
  const int cbl = (ct<4) ? ct*64 : (ct-4)*64;
  const int cbg = (ct<4) ? ct*64 : 256 + (ct-4)*64;
  const int kb = k0c + ks*NKC;
  const uint_t* ap = xcatpk + (size_t)w*18432 + m*32 + quad*8 + (size_t)kb*512;
  const ushort_t* bp0 = Bhi + (size_t)((cbl>>4)+0)*18432 + m*32 + quad*8 + (size_t)kb*512;
  const ushort_t* bp1 = Bhi + (size_t)((cbl>>4)+1)*18432 + m*32 + quad*8 + (size_t)kb*512;
  const ushort_t* bp2 = Bhi + (size_t)((cbl>>4)+2)*18432 + m*32 + quad*8 + (size_t)kb*512;
  const ushort_t* bp3 = Bhi + (size_t)((cbl>>4)+3)*18432 + m*32 + quad*8 + (size_t)kb*512;
  const size_t lod = (size_t)(qw1Tlo - qw1Thi);   // == vw1Tlo - vw1Thi by layout
  floatx4 acc[4];
  #pragma unroll
  for (int i=0;i<4;i++) acc[i] = (floatx4){0.f,0.f,0.f,0.f};
  #pragma unroll
  for (int kc=0; kc<NKC; kc++){
    const uint4 ua0 = *(const uint4*)(ap);
    const uint4 ua1 = *(const uint4*)(ap+4);
    ap += 512;
    short8 ahi, alo;
    UNPACK8(ua0,ua1,ahi,alo)
    const ushort_t* bps[4] = {bp0, bp1, bp2, bp3};
    #pragma unroll
    for (int nt=0; nt<4; nt++){
      const short8 bh = *(const short8*)(bps[nt] + kc*512);
      const short8 bl = *(const short8*)(bps[nt] + kc*512 + lod);
      acc[nt] = __builtin_amdgcn_mfma_f32_16x16x32_bf16(ahi, bh, acc[nt], 0,0,0);
      acc[nt] = __builtin_amdgcn_mfma_f32_16x16x32_bf16(ahi, bl, acc[nt], 0,0,0);
      acc[nt] = __builtin_amdgcn_mfma_f32_16x16x32_bf16(alo, bh, acc[nt], 0,0,0);
    }
  }
  float* pdst = part + (size_t)(slot0+ks)*65536;
  const int crow0 = w*16 + quad*4;
  #pragma unroll
  for (int nt=0; nt<4; nt++){
    const int col = cbg + nt*16 + m;
    #pragma unroll
    for (int r=0;r<4;r++)
      pdst[(size_t)(crow0 + r)*512 + col] = acc[nt][r];
  }
}

// =============== K1: enc (blocks 0..511, XCD-swizzled) + ALL weight converts (512..1471) ===============
__global__ __launch_bounds__(256) void prep_kernel(
    const float* __restrict__ obs,
    const float* __restrict__ enc_w1, const float* __restrict__ enc_b1,
    const float* __restrict__ enc_w2, const float* __restrict__ enc_b2,
    const float* __restrict__ wl1, const float* __restrict__ wr1,
    const float* __restrict__ wl2, const float* __restrict__ wr2,
    const float* __restrict__ q_w1, const float* __restrict__ v_w1,
    ushort_t* __restrict__ wl1Thi, ushort_t* __restrict__ wl1Tlo,
    ushort_t* __restrict__ wr1Thi, ushort_t* __restrict__ wr1Tlo,
    ushort_t* __restrict__ wl2Thi, ushort_t* __restrict__ wl2Tlo,
    ushort_t* __restrict__ wr2Thi, ushort_t* __restrict__ wr2Tlo,
    ushort_t* __restrict__ qw1Thi, ushort_t* __restrict__ qw1Tlo,
    ushort_t* __restrict__ vw1Thi, ushort_t* __restrict__ vw1Tlo,
    uint_t* __restrict__ xpk, uint_t* __restrict__ xcatpk,
    unsigned* __restrict__ adjw, int* __restrict__ aiw)
{
  const int t = threadIdx.x, bid = blockIdx.x;
  if (bid >= 512){
    __shared__ float sm[32][33];
    const int cw = bid - 512;
    const float* in; ushort_t* ohi; ushort_t* olo; int K, N, tt, ktiles;
    if (cw < 64)       { in=wl1;  ohi=wl1Thi; olo=wl1Tlo; K=128;  N=512; tt=cw;     ktiles=4;  }
    else if (cw < 128) { in=wr1;  ohi=wr1Thi; olo=wr1Tlo; K=128;  N=512; tt=cw-64;  ktiles=4;  }
    else if (cw < 384) { in=wl2;  ohi=wl2Thi; olo=wl2Tlo; K=512;  N=512; tt=cw-128; ktiles=16; }
    else if (cw < 640) { in=wr2;  ohi=wr2Thi; olo=wr2Tlo; K=512;  N=512; tt=cw-384; ktiles=16; }
    else if (cw < 800) { in=q_w1; ohi=qw1Thi; olo=qw1Tlo; K=1152; N=256; tt=cw-640; ktiles=20; }  // rows<640 only
    else               { in=v_w1; ohi=vw1Thi; olo=vw1Tlo; K=1152; N=256; tt=cw-800; ktiles=20; }  // rows<640 only
    const int kt = tt % ktiles, nt = tt / ktiles;
    const int r = t>>5, c = t&31;
    #pragma unroll
    for (int i=0;i<4;i++)
      sm[r+i*8][c] = in[(size_t)(kt*32 + r + i*8)*N + nt*32 + c];
    __syncthreads();
    #pragma unroll
    for (int i=0;i<4;i++){
      const int nl = r + i*8;
      const int n  = nt*32 + nl;
      const float f = sm[c][nl];
      const unsigned hb = bf16rne(f);
      const float hf = __uint_as_float(hb<<16);
      const unsigned lb = bf16rne(f - hf);
      const size_t off = (size_t)(n>>4)*(size_t)(16*K) + (size_t)kt*512 + (size_t)(n&15)*32 + c;
      ohi[off] = (ushort_t)hb;
      olo[off] = (ushort_t)lb;
    }
    return;
  }
  __shared__ float s_pos[64];
  __shared__ float s_feats[128];
  __shared__ __align__(16) float s_h[8*132];
  __shared__ int s_ai;
  // XCD swizzle: same-sample blocks 128 apart -> same XCD (bid%8 preserved)
  const int s = bid & 127, g = bid >> 7;
  const float* ob = obs + s*577;

  if (t==0){
    float a = ob[576];
    a = fminf(fmaxf(a, 0.f), 31.f);
    s_ai = (int)a;
    if (g==0) aiw[s] = (int)a;
  }
  if (t < 128){ const int n=t>>4, f=t&15; s_feats[t] = ob[(g*8+n)*18+2+f]; }
  if (g==0 && t>=128 && t<192){ const int u=t-128; s_pos[u] = ob[(u>>1)*18 + (u&1)]; }
  __syncthreads();

  if (g==0 && t < 32){
    const float px = s_pos[2*t], py = s_pos[2*t+1];
    const float R2 = 0.09f;
    unsigned mm = 0u;
    for (int j=0;j<32;j++){
      const float dx = __fsub_rn(px, s_pos[2*j]), dy = __fsub_rn(py, s_pos[2*j+1]);
      const float d2 = __fadd_rn(__fmul_rn(dx,dx), __fmul_rn(dy,dy));
      if (d2 <= R2 || j==t) mm |= (1u<<j);
    }
    adjw[s*32+t] = mm;
  }

  const int n = t>>5, c0 = (t&31)*4;
  {
    float4 a = *(const float4*)(enc_b1+c0);
    #pragma unroll
    for (int f=0; f<16; f++)
      a = fma4(a, s_feats[n*16+f], *(const float4*)(enc_w1 + f*128 + c0));
    *(float4*)&s_h[n*132+c0] = relu4(a);
  }
  __syncthreads();
  {
    float4 a = *(const float4*)(enc_b2+c0);
    for (int k=0;k<128;k+=4){
      const float4 hv = *(const float4*)&s_h[n*132+k];
      a = fma4(a, hv.x, *(const float4*)(enc_w2 + (k+0)*128 + c0));
      a = fma4(a, hv.y, *(const float4*)(enc_w2 + (k+1)*128 + c0));
      a = fma4(a, hv.z, *(const float4*)(enc_w2 + (k+2)*128 + c0));
      a = fma4(a, hv.w, *(const float4*)(enc_w2 + (k+3)*128 + c0));
    }
    a = relu4(a);
    const uint4 p = pack4(a);
    const int i = g*8 + n;
    uint_t* xp = xpk + (size_t)(s*2 + (i>>4))*2048 + (c0>>5)*512 + (i&15)*32 + (c0&31);
    *(uint4*)xp = p;
    if (i == s_ai){
      uint_t* xc = xcatpk + (size_t)(s>>4)*18432 + (c0>>5)*512 + (s&15)*32 + (c0&31);
      *(uint4*)xc = p;
    }
  }
}

// =============== K2: pa1 — pure GAT1 (512 blocks, XCD-swizzled) ===============
__global__ __launch_bounds__(512) void pa1_kernel(
    const uint_t* __restrict__ xpk,
    const ushort_t* __restrict__ wl1Thi, const ushort_t* __restrict__ wl1Tlo,
    const ushort_t* __restrict__ wr1Thi, const ushort_t* __restrict__ wr1Tlo,
    const float* __restrict__ att, const float* __restrict__ bias,
    const unsigned* __restrict__ adjw, const int* __restrict__ aiw,
    uint_t* __restrict__ x2pk, uint_t* __restrict__ xcatpk)
{
  __shared__ __align__(16) float s_gl[32*132];
  __shared__ __align__(16) float s_gr[32*132];
  __shared__ __align__(16) float s_att[128];
  __shared__ __align__(16) float s_b[128];
  __shared__ float s_lg[32*33];
  __shared__ unsigned s_adj[32];
  const int t = threadIdx.x, bid = blockIdx.x;

  // XCD swizzle: same-sample blocks 128 apart -> same XCD
  const int s = bid & 127, h = bid >> 7;
  const int w = t>>6, lane = t&63, m = lane&15, quad = lane>>4;
  const int mat = w>>2, cpair = w&3;   // mat: 0=gl(wl1), 1=gr(wr1); cpair: 32-col chunk

  if (t < 128){ s_att[t] = att[h*128 + t]; s_b[t] = bias[h*128 + t]; }
  if (t >= 224 && t < 256) s_adj[t-224] = adjw[s*32 + (t-224)];
  const int ai = aiw[s];

  const ushort_t* Bhi = (mat==0) ? wl1Thi : wr1Thi;
  const ushort_t* Blo = (mat==0) ? wl1Tlo : wr1Tlo;
  const int nbase = h*8 + cpair*2;
  const uint_t* a0p = xpk + (size_t)(s*2+0)*2048 + m*32 + quad*8;
  const uint_t* a1p = xpk + (size_t)(s*2+1)*2048 + m*32 + quad*8;
  const ushort_t* bp0 = Bhi + (size_t)(nbase+0)*2048 + m*32 + quad*8;
  const ushort_t* bp1 = Bhi + (size_t)(nbase+1)*2048 + m*32 + quad*8;
  const size_t lod = (size_t)(Blo - Bhi);
  floatx4 acc[2][2];
  #pragma unroll
  for (int i=0;i<2;i++)
    #pragma unroll
    for (int j=0;j<2;j++) acc[i][j] = (floatx4){0.f,0.f,0.f,0.f};

  #pragma unroll
  for (int kc=0; kc<4; kc++){
    const uint4 u00 = *(const uint4*)(a0p + kc*512);
    const uint4 u01 = *(const uint4*)(a0p + kc*512 + 4);
    const uint4 u10 = *(const uint4*)(a1p + kc*512);
    const uint4 u11 = *(const uint4*)(a1p + kc*512 + 4);
    short8 ahi0, alo0, ahi1, alo1;
    UNPACK8(u00,u01,ahi0,alo0)
    UNPACK8(u10,u11,ahi1,alo1)
    const ushort_t* bps[2] = {bp0, bp1};
    #pragma unroll
    for (int nt=0; nt<2; nt++){
      const short8 bh = *(const short8*)(bps[nt] + kc*512);
      const short8 bl = *(const short8*)(bps[nt] + kc*512 + lod);
      acc[0][nt] = __builtin_amdgcn_mfma_f32_16x16x32_bf16(ahi0, bh, acc[0][nt], 0,0,0);
      acc[0][nt] = __builtin_amdgcn_mfma_f32_16x16x32_bf16(ahi0, bl, acc[0][nt], 0,0,0);
      acc[0][nt] = __builtin_amdgcn_mfma_f32_16x16x32_bf16(alo0, bh, acc[0][nt], 0,0,0);
      acc[1][nt] = __builtin_amdgcn_mfma_f32_16x16x32_bf16(ahi1, bh, acc[1][nt], 0,0,0);
      acc[1][nt] = __builtin_amdgcn_mfma_f32_16x16x32_bf16(ahi1, bl, acc[1][nt], 0,0,0);
      acc[1][nt] = __builtin_amdgcn_mfma_f32_16x16x32_bf16(alo1, bh, acc[1][nt], 0,0,0);
    }
  }
  {
    float* dst = mat ? s_gr : s_gl;
    const int colbase = cpair*32;
    #pragma unroll
    for (int nt=0; nt<2; nt++){
      const int col = colbase + nt*16 + m;
      #pragma unroll
      for (int r=0;r<4;r++){
        dst[(quad*4+r)*132 + col]      = acc[0][nt][r];
        dst[(16+quad*4+r)*132 + col]   = acc[1][nt][r];
      }
    }
  }
  __syncthreads();

  // logits
  {
    const int i = t>>4, jb = t&15;
    float lacc[2] = {0.f,0.f};
    for (int c=0;c<128;c+=4){
      const float4 g = *(const float4*)&s_gr[i*132+c];
      const float4 a = *(const float4*)&s_att[c];
      #pragma unroll
      for (int mm=0;mm<2;mm++){
        const float4 gj = *(const float4*)&s_gl[(jb+16*mm)*132 + c];
        float ex = g.x+gj.x; ex = fmaxf(ex, 0.2f*ex);
        float ey = g.y+gj.y; ey = fmaxf(ey, 0.2f*ey);
        float ez = g.z+gj.z; ez = fmaxf(ez, 0.2f*ez);
        float ew = g.w+gj.w; ew = fmaxf(ew, 0.2f*ew);
        lacc[mm] += ex*a.x + ey*a.y + ez*a.z + ew*a.w;
      }
    }
    s_lg[i*33 + jb]      = lacc[0];
    s_lg[i*33 + jb + 16] = lacc[1];
  }
  __syncthreads();

  // masked softmax
  #pragma unroll
  for (int rnd=0; rnd<2; rnd++){
    const int i = rnd*16 + (t>>5), j = t&31;
    const float lg = s_lg[i*33+j];
    const bool ok = (s_adj[i]>>j)&1u;
    float v = ok ? lg : -3.0e38f;
    #pragma unroll
    for (int d_=16; d_; d_>>=1) v = fmaxf(v, __shfl_xor(v, d_, 32));
    const float e = ok ? __expf(lg - v) : 0.f;
    float sum = e;
    #pragma unroll
    for (int d_=16; d_; d_>>=1) sum += __shfl_xor(sum, d_, 32);
    s_lg[i*33+j] = e / sum;
  }
  __syncthreads();

  // aggregate -> packed x2 + agent tap
  {
    const int i = t>>4, c0 = (t&15)*8;
    float4 o0 = make_float4(0.f,0.f,0.f,0.f), o1 = o0;
    for (int j=0;j<32;j++){
      const float al = s_lg[i*33+j];
      o0 = fma4(o0, al, *(const float4*)&s_gl[j*132 + c0]);
      o1 = fma4(o1, al, *(const float4*)&s_gl[j*132 + c0 + 4]);
    }
    const float4 b0 = *(const float4*)&s_b[c0];
    const float4 b1 = *(const float4*)&s_b[c0+4];
    o0 = relu4(make_float4(o0.x+b0.x, o0.y+b0.y, o0.z+b0.z, o0.w+b0.w));
    o1 = relu4(make_float4(o1.x+b1.x, o1.y+b1.y, o1.z+b1.z, o1.w+b1.w));
    const uint4 p0 = pack4(o0), p1 = pack4(o1);
    const int kb = h*128 + c0;
    uint_t* xp = x2pk + (size_t)(s*2 + (i>>4))*8192 + (kb>>5)*512 + (i&15)*32 + (kb&31);
    *(uint4*)&xp[0] = p0;
    *(uint4*)&xp[4] = p1;
    if (i == ai){
      const int kk = 128 + kb;
      uint_t* tp = xcatpk + (size_t)(s>>4)*18432 + (kk>>5)*512 + (s&15)*32 + (kk&31);
      *(uint4*)&tp[0] = p0;
      *(uint4*)&tp[4] = p1;
    }
  }
}

// =============== K3: GR = X2_agent(128x512) @ wr2 via MFMA (0..31) + heads k<640 (32..63) ===============
__global__ __launch_bounds__(512) void gr2_kernel(
    const uint_t* __restrict__ xcatpk,
    const ushort_t* __restrict__ wr2Thi, const ushort_t* __restrict__ wr2Tlo,
    const ushort_t* __restrict__ qw1Thi, const ushort_t* __restrict__ qw1Tlo,
    const ushort_t* __restrict__ vw1Thi, const ushort_t* __restrict__ vw1Tlo,
    float* __restrict__ hpart, float* __restrict__ GR)
{
  const int t = threadIdx.x, bid = blockIdx.x;
  if (bid >= 32){
    const int hk = bid - 32;      // ks = hk>>3, ct = hk&7
    hgemm_body<5>(xcatpk, qw1Thi, qw1Tlo, vw1Thi, vw1Tlo, hpart, hk>>3, hk&7, t, 0, 0);
    return;
  }
  const int w = t>>6, lane = t&63, m = lane&15, quad = lane>>4;
  // A: xcat k in [128,640) -> kc base 4. B: wr2 rows k in [0,512).
  const uint_t* ap = xcatpk + (size_t)w*18432 + m*32 + quad*8 + (size_t)4*512;
  const ushort_t* bp = wr2Thi + (size_t)bid*8192 + m*32 + quad*8;
  const size_t lod = (size_t)(wr2Tlo - wr2Thi);
  floatx4 acc = (floatx4){0.f,0.f,0.f,0.f};
  #pragma unroll 4
  for (int kc=0; kc<16; kc++){
    const uint4 ua0 = *(const uint4*)(ap + kc*512);
    const uint4 ua1 = *(const uint4*)(ap + kc*512 + 4);
    short8 ahi, alo;
    UNPACK8(ua0,ua1,ahi,alo)
    const short8 bh = *(const short8*)(bp + kc*512);
    const short8 bl = *(const short8*)(bp + kc*512 + lod);
    acc = __builtin_amdgcn_mfma_f32_16x16x32_bf16(ahi, bh, acc, 0,0,0);
    acc = __builtin_amdgcn_mfma_f32_16x16x32_bf16(ahi, bl, acc, 0,0,0);
    acc = __builtin_amdgcn_mfma_f32_16x16x32_bf16(alo, bh, acc, 0,0,0);
  }
  const int row0 = w*16 + quad*4, col = bid*16 + m;
  #pragma unroll
  for (int r=0;r<4;r++)
    GR[(size_t)(row0 + r)*512 + col] = acc[r];
}

// =============== K4: pa2 — lean GAT2 (512 blocks, XCD-swizzled), writes X3 fp32 ===============
__global__ __launch_bounds__(512) void pa2_kernel(
    const uint_t* __restrict__ x2pk,
    const ushort_t* __restrict__ wl2Thi, const ushort_t* __restrict__ wl2Tlo,
    const float* __restrict__ GR,
    const float* __restrict__ att2, const float* __restrict__ bias2,
    const unsigned* __restrict__ adjw, const int* __restrict__ aiw,
    float* __restrict__ X3)
{
  __shared__ __align__(16) float s_gl[32*132];
  __shared__ __align__(16) float s_p2[128];
  __shared__ __align__(16) float s_at[128];
  __shared__ __align__(16) float s_bb[128];
  __shared__ float s_lg[32];
  __shared__ float s_al[32];
  const int t = threadIdx.x, bid = blockIdx.x;
  // XCD swizzle: same-sample blocks 128 apart -> same XCD
  const int s = bid & 127, h = bid >> 7;
  const int w = t>>6, lane = t&63, m = lane&15, quad = lane>>4;
  (void)lane;
  const int ai = aiw[s];
  const unsigned arow = adjw[s*32+ai];

  if (t < 128){
    s_p2[t] = GR[(size_t)s*512 + h*128 + t];
    s_at[t] = att2[h*128+t];
    s_bb[t] = bias2[h*128+t];
  }

  // gl2 = x2 @ wl2 : each wave owns one 16-col tile for full K=512.
  const uint_t* a0p = x2pk + (size_t)(s*2+0)*8192 + m*32 + quad*8;
  const uint_t* a1p = x2pk + (size_t)(s*2+1)*8192 + m*32 + quad*8;
  const ushort_t* bq = wl2Thi + (size_t)(h*8 + w)*8192 + m*32 + quad*8;
  const size_t lod = (size_t)(wl2Tlo - wl2Thi);
  floatx4 acc0 = (floatx4){0.f,0.f,0.f,0.f}, acc1 = acc0;
  #pragma unroll 4
  for (int kc=0; kc<16; kc++){
    const uint4 u00 = *(const uint4*)(a0p + kc*512);
    const uint4 u01 = *(const uint4*)(a0p + kc*512 + 4);
    const uint4 u10 = *(const uint4*)(a1p + kc*512);
    const uint4 u11 = *(const uint4*)(a1p + kc*512 + 4);
    short8 ahi0, alo0, ahi1, alo1;
    UNPACK8(u00,u01,ahi0,alo0)
    UNPACK8(u10,u11,ahi1,alo1)
    const short8 bh = *(const short8*)(bq + kc*512);
    const short8 bl = *(const short8*)(bq + kc*512 + lod);
    acc0 = __builtin_amdgcn_mfma_f32_16x16x32_bf16(ahi0, bh, acc0, 0,0,0);
    acc0 = __builtin_amdgcn_mfma_f32_16x16x32_bf16(ahi0, bl, acc0, 0,0,0);
    acc0 = __builtin_amdgcn_mfma_f32_16x16x32_bf16(alo0, bh, acc0, 0,0,0);
    acc1 = __builtin_amdgcn_mfma_f32_16x16x32_bf16(ahi1, bh, acc1, 0,0,0);
    acc1 = __builtin_amdgcn_mfma_f32_16x16x32_bf16(ahi1, bl, acc1, 0,0,0);
    acc1 = __builtin_amdgcn_mfma_f32_16x16x32_bf16(alo1, bh, acc1, 0,0,0);
  }
  {
    const int col = w*16 + m;
    #pragma unroll
    for (int r=0;r<4;r++){
      s_gl[(quad*4+r)*132 + col]    = acc0[r];
      s_gl[(16+quad*4+r)*132 + col] = acc1[r];
    }
  }
  __syncthreads();

  if (t < 256){
    const int j = t>>3, pq = t&7;
    float sum = 0.f;
    #pragma unroll
    for (int q=0;q<4;q++){
      const int c = pq*16 + q*4;
      const float4 g = *(const float4*)&s_gl[j*132 + c];
      const float4 r = *(const float4*)&s_p2[c];
      const float4 a = *(const float4*)&s_at[c];
      float e0 = r.x+g.x; e0 = fmaxf(e0, 0.2f*e0);
      float e1 = r.y+g.y; e1 = fmaxf(e1, 0.2f*e1);
      float e2 = r.z+g.z; e2 = fmaxf(e2, 0.2f*e2);
      float e3 = r.w+g.w; e3 = fmaxf(e3, 0.2f*e3);
      sum += e0*a.x + e1*a.y + e2*a.z + e3*a.w;
    }
    sum += __shfl_xor(sum,1,64);
    sum += __shfl_xor(sum,2,64);
    sum += __shfl_xor(sum,4,64);
    if (pq==0) s_lg[j] = sum;
  }
  __syncthreads();
  if (t < 32){
    const float lg = s_lg[t];
    const bool ok = (arow>>t)&1u;
    float v = ok ? lg : -3.0e38f;
    #pragma unroll
    for (int d_=16; d_; d_>>=1) v = fmaxf(v, __shfl_xor(v, d_, 32));
    const float e = ok ? __expf(lg - v) : 0.f;
    float sm = e;
    #pragma unroll
    for (int d_=16; d_; d_>>=1) sm += __shfl_xor(sm, d_, 32);
    s_al[t] = e / sm;
  }
  __syncthreads();
  if (t < 128){
    float acc2 = 0.f;
    #pragma unroll 8
    for (int j=0;j<32;j++) acc2 += s_al[j] * s_gl[j*132 + t];
    X3[(size_t)s*512 + h*128 + t] = fmaxf(acc2 + s_bb[t], 0.f);
  }
}

// =============== K5: hepi — per-sample: k<640 partial sums + x3 GEMV (K=512) + combine ===============
__global__ __launch_bounds__(512) void hepi_kernel(
    const float* __restrict__ X3, const float* __restrict__ hpart,
    const float* __restrict__ q_w1, const float* __restrict__ q_b1,
    const float* __restrict__ q_w2, const float* __restrict__ q_b2,
    const float* __restrict__ v_w1, const float* __restrict__ v_b1,
    const float* __restrict__ v_w2, const float* __restrict__ v_b2,
    float* __restrict__ out)
{
  __shared__ __align__(16) float s_x3[512];
  __shared__ float s_p6[8*6];
  const int t = threadIdx.x, s = blockIdx.x;
  const int w = t>>6, lane = t&63;

  s_x3[t] = X3[(size_t)s*512 + t];
  __syncthreads();

  // col t: 0..255 q, 256..511 v (matches hpart layout)
  float val;
  {
    const int col = t & 255;
    float acc = (t < 256) ? q_b1[col] : v_b1[col];
    #pragma unroll
    for (int ks=0; ks<4; ks++)
      acc += hpart[(size_t)ks*65536 + (size_t)s*512 + t];
    const float* Wp = ((t < 256) ? q_w1 : v_w1) + (size_t)640*256 + col;
    #pragma unroll 8
    for (int k=0;k<512;k++) acc += s_x3[k] * Wp[(size_t)k*256];
    val = fmaxf(acc, 0.f);
  }

  // dueling combine
  float p[6];
  #pragma unroll
  for (int o=0;o<6;o++) p[o] = 0.f;
  if (t < 256){
    #pragma unroll
    for (int o=0;o<5;o++) p[o] = val * q_w2[t*5+o];
  } else {
    p[5] = val * v_w2[t-256];
  }
  #pragma unroll
  for (int d_=32; d_; d_>>=1){
    #pragma unroll
    for (int o=0;o<6;o++) p[o] += __shfl_xor(p[o], d_, 64);
  }
  if (lane==0){
    #pragma unroll
    for (int o=0;o<6;o++) s_p6[w*6+o] = p[o];
  }
  __syncthreads();
  if (t < 6){
    float v = 0.f;
    #pragma unroll
    for (int ww=0; ww<8; ww++) v += s_p6[ww*6 + t];
    s_p6[t] = v;
  }
  __syncthreads();
  if (t < 5){
    const float q0 = s_p6[0]+q_b2[0], q1 = s_p6[1]+q_b2[1], q2 = s_p6[2]+q_b2[2],
                q3 = s_p6[3]+q_b2[3], q4 = s_p6[4]+q_b2[4];
    const float mean = (q0+q1+q2+q3+q4) / 5.0f;
    const float v = s_p6[5] + v_b2[0];
    const float qt = (t==0?q0:t==1?q1:t==2?q2:t==3?q3:q4);
    out[s*5+t] = qt - mean + v;
  }
}

extern "C" void kernel_launch(void* const* d_in, const int* in_sizes, int n_in,
                              void* d_out, int out_size, void* d_ws, size_t ws_size,
                              hipStream_t stream) {
  (void)n_in; (void)out_size; (void)ws_size;
  const float* obs    = (const float*)d_in[0];
  const float* enc_w1 = (const float*)d_in[1];
  const float* enc_b1 = (const float*)d_in[2];
  const float* enc_w2 = (const float*)d_in[3];
  const float* enc_b2 = (const float*)d_in[4];
  const float* wl1    = (const float*)d_in[5];
  const float* wr1    = (const float*)d_in[6];
  const float* att1   = (const float*)d_in[7];
  const float* bias1  = (const float*)d_in[8];
  const float* wl2    = (const float*)d_in[9];
  const float* wr2    = (const float*)d_in[10];
  const float* att2   = (const float*)d_in[11];
  const float* bias2  = (const float*)d_in[12];
  const float* q_w1   = (const float*)d_in[13];
  const float* q_b1   = (const float*)d_in[14];
  const float* q_w2   = (const float*)d_in[15];
  const float* q_b2   = (const float*)d_in[16];
  const float* v_w1   = (const float*)d_in[17];
  const float* v_b1   = (const float*)d_in[18];
  const float* v_w2   = (const float*)d_in[19];
  const float* v_b2   = (const float*)d_in[20];

  // Workspace layout (total ~17.6 MB; ws is ~268 MB per harness fill)
  char* ws = (char*)d_ws;
  uint_t*   x_pk    = (uint_t*)  (ws + 0);           // 2,097,152
  uint_t*   xcat_pk = (uint_t*)  (ws + 2097152);     //   589,824
  unsigned* adjw    = (unsigned*)(ws + 2686976);     //    16,384
  int*      aiw     = (int*)     (ws + 2703360);     //       512
  uint_t*   x2_pk   = (uint_t*)  (ws + 2703872);     // 8,388,608
  ushort_t* wl1Thi  = (ushort_t*)(ws + 11092480);    //   131,072
  ushort_t* wl1Tlo  = (ushort_t*)(ws + 11223552);    //   131,072
  ushort_t* wr1Thi  = (ushort_t*)(ws + 11354624);    //   131,072
  ushort_t* wr1Tlo  = (ushort_t*)(ws + 11485696);    //   131,072
  ushort_t* wl2Thi  = (ushort_t*)(ws + 11616768);    //   524,288
  ushort_t* wl2Tlo  = (ushort_t*)(ws + 12141056);    //   524,288
  ushort_t* qw1Thi  = (ushort_t*)(ws + 12665344);    //   589,824
  ushort_t* qw1Tlo  = (ushort_t*)(ws + 13255168);    //   589,824
  ushort_t* vw1Thi  = (ushort_t*)(ws + 13844992);    //   589,824
  ushort_t* vw1Tlo  = (ushort_t*)(ws + 14434816);    //   589,824
  ushort_t* wr2Thi  = (ushort_t*)(ws + 15024640);    //   524,288
  ushort_t* wr2Tlo  = (ushort_t*)(ws + 15548928);    //   524,288
  float*    GR      = (float*)   (ws + 16073216);    //   262,144
  float*    hpart   = (float*)   (ws + 16335360);    // 1,048,576 (4 slots)
  float*    X3      = (float*)   (ws + 17383936);    //   262,144 (ends 17,646,080)

  prep_kernel<<<512 + 960, 256, 0, stream>>>(obs, enc_w1, enc_b1, enc_w2, enc_b2,
      wl1, wr1, wl2, wr2, q_w1, v_w1,
      wl1Thi, wl1Tlo, wr1Thi, wr1Tlo, wl2Thi, wl2Tlo, wr2Thi, wr2Tlo,
      qw1Thi, qw1Tlo, vw1Thi, vw1Tlo,
      x_pk, xcat_pk, adjw, aiw);

  pa1_kernel<<<512, 512, 0, stream>>>(x_pk, wl1Thi, wl1Tlo, wr1Thi, wr1Tlo,
      att1, bias1, adjw, aiw, x2_pk, xcat_pk);

  gr2_kernel<<<64, 512, 0, stream>>>(xcat_pk, wr2Thi, wr2Tlo,
      qw1Thi, qw1Tlo, vw1Thi, vw1Tlo, hpart, GR);

  pa2_kernel<<<512, 512, 0, stream>>>(x2_pk, wl2Thi, wl2Tlo, GR,
      att2, bias2, adjw, aiw, X3);

  hepi_kernel<<<128, 512, 0, stream>>>(X3, hpart,
      q_w1, q_b1, q_w2, q_b2, v_w1, v_b1, v_w2, v_b2,
      (float*)d_out);
}

// Round 7
// 174.930 us; speedup vs baseline: 5.5272x; 1.1847x over previous
//
#include <hip/hip_runtime.h>
#include <hip/hip_bf16.h>

typedef unsigned int uint_t;
typedef unsigned short ushort_t;
typedef __attribute__((ext_vector_type(8))) short short8;
typedef __attribute__((ext_vector_type(4))) float floatx4;

__device__ __forceinline__ float4 fma4(float4 a, float s, float4 w){
  a.x += s*w.x; a.y += s*w.y; a.z += s*w.z; a.w += s*w.w; return a;
}
__device__ __forceinline__ float4 relu4(float4 a){
  return make_float4(fmaxf(a.x,0.f),fmaxf(a.y,0.f),fmaxf(a.z,0.f),fmaxf(a.w,0.f));
}
__device__ __forceinline__ unsigned bf16rne(float f){
  unsigned u = __float_as_uint(f);
  return (u + 0x7fffu + ((u>>16)&1u)) >> 16;
}
__device__ __forceinline__ uint_t packbf(float f){
  unsigned hb = bf16rne(f);
  float hf = __uint_as_float(hb<<16);
  unsigned lb = bf16rne(f - hf);
  return (hb<<16) | lb;
}
__device__ __forceinline__ uint4 pack4(float4 v){
  uint4 u; u.x=packbf(v.x); u.y=packbf(v.y); u.z=packbf(v.z); u.w=packbf(v.w); return u;
}
__device__ __forceinline__ float unpk(uint_t u){
  return __uint_as_float(u & 0xffff0000u) + __uint_as_float(u<<16);
}
#define UNPACK8(u0,u1,hi,lo) \
  hi[0]=(short)(u0.x>>16); lo[0]=(short)u0.x; \
  hi[1]=(short)(u0.y>>16); lo[1]=(short)u0.y; \
  hi[2]=(short)(u0.z>>16); lo[2]=(short)u0.z; \
  hi[3]=(short)(u0.w>>16); lo[3]=(short)u0.w; \
  hi[4]=(short)(u1.x>>16); lo[4]=(short)u1.x; \
  hi[5]=(short)(u1.y>>16); lo[5]=(short)u1.y; \
  hi[6]=(short)(u1.z>>16); lo[6]=(short)u1.z; \
  hi[7]=(short)(u1.w>>16); lo[7]=(short)u1.w;

// Fragment-order offset: off(n,k) = (n>>4)*16*K + (k>>5)*512 + (n&15)*32 + (k&31)
// LDS A-stage swizzle (bank-conflict fix): word u within a 512-word row is stored at
//   u ^ (((u>>5)&7)<<2).  Read base sw = (m*32+quad*8) ^ ((m&7)<<2); second uint4 at sw^4.

// heads GEMM K-window body: job (ks, ct in 0..7), 512 threads (8 waves = 8 row-blocks).
template<int NKC>
__device__ __forceinline__ void hgemm_body(
    const uint_t* __restrict__ xcatpk,
    const ushort_t* __restrict__ qw1Thi, const ushort_t* __restrict__ qw1Tlo,
    const ushort_t* __restrict__ vw1Thi, const ushort_t* __restrict__ vw1Tlo,
    float* __restrict__ part, int ks, int ct, int t, int k0c, int slot0)
{
  const int w = t>>6, lane = t&63, m = lane&15, quad = lane>>4;
  const ushort_t* Bhi = (ct<4) ? qw1Thi : vw1Thi;
  const int cbl = (ct<4) ? ct*64 : (ct-4)*64;
  const int cbg = (ct<4) ? ct*64 : 256 + (ct-4)*64;
  const int kb = k0c + ks*NKC;
  const uint_t* ap = xcatpk + (size_t)w*18432 + m*32 + quad*8 + (size_t)kb*512;
  const ushort_t* bp0 = Bhi + (size_t)((cbl>>4)+0)*18432 + m*32 + quad*8 + (size_t)kb*512;
  const ushort_t* bp1 = Bhi + (size_t)((cbl>>4)+1)*18432 + m*32 + quad*8 + (size_t)kb*512;
  const ushort_t* bp2 = Bhi + (size_t)((cbl>>4)+2)*18432 + m*32 + quad*8 + (size_t)kb*512;
  const ushort_t* bp3 = Bhi + (size_t)((cbl>>4)+3)*18432 + m*32 + quad*8 + (size_t)kb*512;
  const size_t lod = (size_t)(qw1Tlo - qw1Thi);
  floatx4 acc[4];
  #pragma unroll
  for (int i=0;i<4;i++) acc[i] = (floatx4){0.f,0.f,0.f,0.f};
  #pragma unroll
  for (int kc=0; kc<NKC; kc++){
    const uint4 ua0 = *(const uint4*)(ap);
    const uint4 ua1 = *(const uint4*)(ap+4);
    ap += 512;
    short8 ahi, alo;
    UNPACK8(ua0,ua1,ahi,alo)
    const ushort_t* bps[4] = {bp0, bp1, bp2, bp3};
    #pragma unroll
    for (int nt=0; nt<4; nt++){
      const short8 bh = *(const short8*)(bps[nt] + kc*512);
      const short8 bl = *(const short8*)(bps[nt] + kc*512 + lod);
      acc[nt] = __builtin_amdgcn_mfma_f32_16x16x32_bf16(ahi, bh, acc[nt], 0,0,0);
      acc[nt] = __builtin_amdgcn_mfma_f32_16x16x32_bf16(ahi, bl, acc[nt], 0,0,0);
      acc[nt] = __builtin_amdgcn_mfma_f32_16x16x32_bf16(alo, bh, acc[nt], 0,0,0);
    }
  }
  float* pdst = part + (size_t)(slot0+ks)*65536;
  const int crow0 = w*16 + quad*4;
  #pragma unroll
  for (int nt=0; nt<4; nt++){
    const int col = cbg + nt*16 + m;
    #pragma unroll
    for (int r=0;r<4;r++)
      pdst[(size_t)(crow0 + r)*512 + col] = acc[nt][r];
  }
}

// =============== K1: enc (blocks 0..511, XCD-swizzled) + ALL weight converts (512..1471) ===============
__global__ __launch_bounds__(256) void prep_kernel(
    const float* __restrict__ obs,
    const float* __restrict__ enc_w1, const float* __restrict__ enc_b1,
    const float* __restrict__ enc_w2, const float* __restrict__ enc_b2,
    const float* __restrict__ wl1, const float* __restrict__ wr1,
    const float* __restrict__ wl2, const float* __restrict__ wr2,
    const float* __restrict__ q_w1, const float* __restrict__ v_w1,
    ushort_t* __restrict__ wl1Thi, ushort_t* __restrict__ wl1Tlo,
    ushort_t* __restrict__ wr1Thi, ushort_t* __restrict__ wr1Tlo,
    ushort_t* __restrict__ wl2Thi, ushort_t* __restrict__ wl2Tlo,
    ushort_t* __restrict__ wr2Thi, ushort_t* __restrict__ wr2Tlo,
    ushort_t* __restrict__ qw1Thi, ushort_t* __restrict__ qw1Tlo,
    ushort_t* __restrict__ vw1Thi, ushort_t* __restrict__ vw1Tlo,
    uint_t* __restrict__ xpk, uint_t* __restrict__ xcatpk,
    unsigned* __restrict__ adjw, int* __restrict__ aiw)
{
  const int t = threadIdx.x, bid = blockIdx.x;
  if (bid >= 512){
    __shared__ float sm[32][33];
    const int cw = bid - 512;
    const float* in; ushort_t* ohi; ushort_t* olo; int K, N, tt, ktiles;
    if (cw < 64)       { in=wl1;  ohi=wl1Thi; olo=wl1Tlo; K=128;  N=512; tt=cw;     ktiles=4;  }
    else if (cw < 128) { in=wr1;  ohi=wr1Thi; olo=wr1Tlo; K=128;  N=512; tt=cw-64;  ktiles=4;  }
    else if (cw < 384) { in=wl2;  ohi=wl2Thi; olo=wl2Tlo; K=512;  N=512; tt=cw-128; ktiles=16; }
    else if (cw < 640) { in=wr2;  ohi=wr2Thi; olo=wr2Tlo; K=512;  N=512; tt=cw-384; ktiles=16; }
    else if (cw < 800) { in=q_w1; ohi=qw1Thi; olo=qw1Tlo; K=1152; N=256; tt=cw-640; ktiles=20; }  // rows<640 only
    else               { in=v_w1; ohi=vw1Thi; olo=vw1Tlo; K=1152; N=256; tt=cw-800; ktiles=20; }  // rows<640 only
    const int kt = tt % ktiles, nt = tt / ktiles;
    const int r = t>>5, c = t&31;
    #pragma unroll
    for (int i=0;i<4;i++)
      sm[r+i*8][c] = in[(size_t)(kt*32 + r + i*8)*N + nt*32 + c];
    __syncthreads();
    #pragma unroll
    for (int i=0;i<4;i++){
      const int nl = r + i*8;
      const int n  = nt*32 + nl;
      const float f = sm[c][nl];
      const unsigned hb = bf16rne(f);
      const float hf = __uint_as_float(hb<<16);
      const unsigned lb = bf16rne(f - hf);
      const size_t off = (size_t)(n>>4)*(size_t)(16*K) + (size_t)kt*512 + (size_t)(n&15)*32 + c;
      ohi[off] = (ushort_t)hb;
      olo[off] = (ushort_t)lb;
    }
    return;
  }
  __shared__ float s_pos[64];
  __shared__ float s_feats[128];
  __shared__ __align__(16) float s_h[8*132];
  __shared__ int s_ai;
  // XCD swizzle: same-sample blocks 128 apart -> same XCD (bid%8 preserved)
  const int s = bid & 127, g = bid >> 7;
  const float* ob = obs + s*577;

  if (t==0){
    float a = ob[576];
    a = fminf(fmaxf(a, 0.f), 31.f);
    s_ai = (int)a;
    if (g==0) aiw[s] = (int)a;
  }
  if (t < 128){ const int n=t>>4, f=t&15; s_feats[t] = ob[(g*8+n)*18+2+f]; }
  if (g==0 && t>=128 && t<192){ const int u=t-128; s_pos[u] = ob[(u>>1)*18 + (u&1)]; }
  __syncthreads();

  if (g==0 && t < 32){
    const float px = s_pos[2*t], py = s_pos[2*t+1];
    const float R2 = 0.09f;
    unsigned mm = 0u;
    for (int j=0;j<32;j++){
      const float dx = __fsub_rn(px, s_pos[2*j]), dy = __fsub_rn(py, s_pos[2*j+1]);
      const float d2 = __fadd_rn(__fmul_rn(dx,dx), __fmul_rn(dy,dy));
      if (d2 <= R2 || j==t) mm |= (1u<<j);
    }
    adjw[s*32+t] = mm;
  }

  const int n = t>>5, c0 = (t&31)*4;
  {
    float4 a = *(const float4*)(enc_b1+c0);
    #pragma unroll
    for (int f=0; f<16; f++)
      a = fma4(a, s_feats[n*16+f], *(const float4*)(enc_w1 + f*128 + c0));
    *(float4*)&s_h[n*132+c0] = relu4(a);
  }
  __syncthreads();
  {
    float4 a = *(const float4*)(enc_b2+c0);
    #pragma unroll 4
    for (int k=0;k<128;k+=4){
      const float4 hv = *(const float4*)&s_h[n*132+k];
      a = fma4(a, hv.x, *(const float4*)(enc_w2 + (k+0)*128 + c0));
      a = fma4(a, hv.y, *(const float4*)(enc_w2 + (k+1)*128 + c0));
      a = fma4(a, hv.z, *(const float4*)(enc_w2 + (k+2)*128 + c0));
      a = fma4(a, hv.w, *(const float4*)(enc_w2 + (k+3)*128 + c0));
    }
    a = relu4(a);
    const uint4 p = pack4(a);
    const int i = g*8 + n;
    uint_t* xp = xpk + (size_t)(s*2 + (i>>4))*2048 + (c0>>5)*512 + (i&15)*32 + (c0&31);
    *(uint4*)xp = p;
    if (i == s_ai){
      uint_t* xc = xcatpk + (size_t)(s>>4)*18432 + (c0>>5)*512 + (s&15)*32 + (c0&31);
      *(uint4*)xc = p;
    }
  }
}

// =============== K2: pa1 — GAT1 (512 blocks, XCD-swizzled), A staged in LDS ===============
__global__ __launch_bounds__(512) void pa1_kernel(
    const uint_t* __restrict__ xpk,
    const ushort_t* __restrict__ wl1Thi, const ushort_t* __restrict__ wl1Tlo,
    const ushort_t* __restrict__ wr1Thi, const ushort_t* __restrict__ wr1Tlo,
    const float* __restrict__ att, const float* __restrict__ bias,
    const unsigned* __restrict__ adjw, const int* __restrict__ aiw,
    uint_t* __restrict__ x2pk, uint_t* __restrict__ xcatpk)
{
  __shared__ __align__(16) uint_t s_ax[4096];   // 16KB: A = xpk[s] (4 kc x 2 rows x 512), swizzled
  __shared__ __align__(16) float s_gl[32*132];
  __shared__ __align__(16) float s_gr[32*132];
  __shared__ __align__(16) float s_att[128];
  __shared__ __align__(16) float s_b[128];
  __shared__ float s_lg[32*33];
  __shared__ unsigned s_adj[32];
  const int t = threadIdx.x, bid = blockIdx.x;

  // XCD swizzle: same-sample blocks 128 apart -> same XCD
  const int s = bid & 127, h = bid >> 7;
  const int w = t>>6, lane = t&63, m = lane&15, quad = lane>>4;
  const int mat = w>>2, cpair = w&3;   // mat: 0=gl(wl1), 1=gr(wr1); cpair: 32-col chunk

  if (t < 128){ s_att[t] = att[h*128 + t]; s_b[t] = bias[h*128 + t]; }
  if (t >= 224 && t < 256) s_adj[t-224] = adjw[s*32 + (t-224)];
  const int ai = aiw[s];

  // cooperative A stage: 4096 words, 8 per thread (2 x uint4), swizzled
  #pragma unroll
  for (int j=0;j<2;j++){
    const int W = t*8 + j*4;
    const int kcl = W>>10, rp = (W>>9)&1, u = W&511;
    const int du = u ^ (((u>>5)&7)<<2);
    *(uint4*)&s_ax[kcl*1024 + rp*512 + du] =
      *(const uint4*)(xpk + (size_t)(s*2+rp)*2048 + (size_t)kcl*512 + u);
  }

  const ushort_t* Bhi = (mat==0) ? wl1Thi : wr1Thi;
  const ushort_t* Blo = (mat==0) ? wl1Tlo : wr1Tlo;
  const int nbase = h*8 + cpair*2;
  const ushort_t* bp0 = Bhi + (size_t)(nbase+0)*2048 + m*32 + quad*8;
  const ushort_t* bp1 = Bhi + (size_t)(nbase+1)*2048 + m*32 + quad*8;
  const size_t lod = (size_t)(Blo - Bhi);
  const int sw = (m*32 + quad*8) ^ ((m&7)<<2);
  floatx4 acc[2][2];
  #pragma unroll
  for (int i=0;i<2;i++)
    #pragma unroll
    for (int j=0;j<2;j++) acc[i][j] = (floatx4){0.f,0.f,0.f,0.f};

  __syncthreads();

  #pragma unroll
  for (int kc=0; kc<4; kc++){
    const uint4 u00 = *(const uint4*)&s_ax[kc*1024 + sw];
    const uint4 u01 = *(const uint4*)&s_ax[kc*1024 + (sw^4)];
    const uint4 u10 = *(const uint4*)&s_ax[kc*1024 + 512 + sw];
    const uint4 u11 = *(const uint4*)&s_ax[kc*1024 + 512 + (sw^4)];
    short8 ahi0, alo0, ahi1, alo1;
    UNPACK8(u00,u01,ahi0,alo0)
    UNPACK8(u10,u11,ahi1,alo1)
    const ushort_t* bps[2] = {bp0, bp1};
    #pragma unroll
    for (int nt=0; nt<2; nt++){
      const short8 bh = *(const short8*)(bps[nt] + kc*512);
      const short8 bl = *(const short8*)(bps[nt] + kc*512 + lod);
      acc[0][nt] = __builtin_amdgcn_mfma_f32_16x16x32_bf16(ahi0, bh, acc[0][nt], 0,0,0);
      acc[0][nt] = __builtin_amdgcn_mfma_f32_16x16x32_bf16(ahi0, bl, acc[0][nt], 0,0,0);
      acc[0][nt] = __builtin_amdgcn_mfma_f32_16x16x32_bf16(alo0, bh, acc[0][nt], 0,0,0);
      acc[1][nt] = __builtin_amdgcn_mfma_f32_16x16x32_bf16(ahi1, bh, acc[1][nt], 0,0,0);
      acc[1][nt] = __builtin_amdgcn_mfma_f32_16x16x32_bf16(ahi1, bl, acc[1][nt], 0,0,0);
      acc[1][nt] = __builtin_amdgcn_mfma_f32_16x16x32_bf16(alo1, bh, acc[1][nt], 0,0,0);
    }
  }
  {
    float* dst = mat ? s_gr : s_gl;
    const int colbase = cpair*32;
    #pragma unroll
    for (int nt=0; nt<2; nt++){
      const int col = colbase + nt*16 + m;
      #pragma unroll
      for (int r=0;r<4;r++){
        dst[(quad*4+r)*132 + col]      = acc[0][nt][r];
        dst[(16+quad*4+r)*132 + col]   = acc[1][nt][r];
      }
    }
  }
  __syncthreads();

  // logits
  {
    const int i = t>>4, jb = t&15;
    float lacc[2] = {0.f,0.f};
    for (int c=0;c<128;c+=4){
      const float4 g = *(const float4*)&s_gr[i*132+c];
      const float4 a = *(const float4*)&s_att[c];
      #pragma unroll
      for (int mm=0;mm<2;mm++){
        const float4 gj = *(const float4*)&s_gl[(jb+16*mm)*132 + c];
        float ex = g.x+gj.x; ex = fmaxf(ex, 0.2f*ex);
        float ey = g.y+gj.y; ey = fmaxf(ey, 0.2f*ey);
        float ez = g.z+gj.z; ez = fmaxf(ez, 0.2f*ez);
        float ew = g.w+gj.w; ew = fmaxf(ew, 0.2f*ew);
        lacc[mm] += ex*a.x + ey*a.y + ez*a.z + ew*a.w;
      }
    }
    s_lg[i*33 + jb]      = lacc[0];
    s_lg[i*33 + jb + 16] = lacc[1];
  }
  __syncthreads();

  // masked softmax
  #pragma unroll
  for (int rnd=0; rnd<2; rnd++){
    const int i = rnd*16 + (t>>5), j = t&31;
    const float lg = s_lg[i*33+j];
    const bool ok = (s_adj[i]>>j)&1u;
    float v = ok ? lg : -3.0e38f;
    #pragma unroll
    for (int d_=16; d_; d_>>=1) v = fmaxf(v, __shfl_xor(v, d_, 32));
    const float e = ok ? __expf(lg - v) : 0.f;
    float sum = e;
    #pragma unroll
    for (int d_=16; d_; d_>>=1) sum += __shfl_xor(sum, d_, 32);
    s_lg[i*33+j] = e / sum;
  }
  __syncthreads();

  // aggregate -> packed x2 + agent tap
  {
    const int i = t>>4, c0 = (t&15)*8;
    float4 o0 = make_float4(0.f,0.f,0.f,0.f), o1 = o0;
    for (int j=0;j<32;j++){
      const float al = s_lg[i*33+j];
      o0 = fma4(o0, al, *(const float4*)&s_gl[j*132 + c0]);
      o1 = fma4(o1, al, *(const float4*)&s_gl[j*132 + c0 + 4]);
    }
    const float4 b0 = *(const float4*)&s_b[c0];
    const float4 b1 = *(const float4*)&s_b[c0+4];
    o0 = relu4(make_float4(o0.x+b0.x, o0.y+b0.y, o0.z+b0.z, o0.w+b0.w));
    o1 = relu4(make_float4(o1.x+b1.x, o1.y+b1.y, o1.z+b1.z, o1.w+b1.w));
    const uint4 p0 = pack4(o0), p1 = pack4(o1);
    const int kb = h*128 + c0;
    uint_t* xp = x2pk + (size_t)(s*2 + (i>>4))*8192 + (kb>>5)*512 + (i&15)*32 + (kb&31);
    *(uint4*)&xp[0] = p0;
    *(uint4*)&xp[4] = p1;
    if (i == ai){
      const int kk = 128 + kb;
      uint_t* tp = xcatpk + (size_t)(s>>4)*18432 + (kk>>5)*512 + (s&15)*32 + (kk&31);
      *(uint4*)&tp[0] = p0;
      *(uint4*)&tp[4] = p1;
    }
  }
}

// =============== K3: GR = X2_agent(128x512) @ wr2 via MFMA (0..31) + heads k<640 (32..63) ===============
__global__ __launch_bounds__(512) void gr2_kernel(
    const uint_t* __restrict__ xcatpk,
    const ushort_t* __restrict__ wr2Thi, const ushort_t* __restrict__ wr2Tlo,
    const ushort_t* __restrict__ qw1Thi, const ushort_t* __restrict__ qw1Tlo,
    const ushort_t* __restrict__ vw1Thi, const ushort_t* __restrict__ vw1Tlo,
    float* __restrict__ hpart, float* __restrict__ GR)
{
  const int t = threadIdx.x, bid = blockIdx.x;
  if (bid >= 32){
    const int hk = bid - 32;      // ks = hk>>3, ct = hk&7
    hgemm_body<5>(xcatpk, qw1Thi, qw1Tlo, vw1Thi, vw1Tlo, hpart, hk>>3, hk&7, t, 0, 0);
    return;
  }
  const int w = t>>6, lane = t&63, m = lane&15, quad = lane>>4;
  // A: xcat k in [128,640) -> kc base 4. B: wr2 rows k in [0,512).
  const uint_t* ap = xcatpk + (size_t)w*18432 + m*32 + quad*8 + (size_t)4*512;
  const ushort_t* bp = wr2Thi + (size_t)bid*8192 + m*32 + quad*8;
  const size_t lod = (size_t)(wr2Tlo - wr2Thi);
  floatx4 acc = (floatx4){0.f,0.f,0.f,0.f};
  #pragma unroll 4
  for (int kc=0; kc<16; kc++){
    const uint4 ua0 = *(const uint4*)(ap + kc*512);
    const uint4 ua1 = *(const uint4*)(ap + kc*512 + 4);
    short8 ahi, alo;
    UNPACK8(ua0,ua1,ahi,alo)
    const short8 bh = *(const short8*)(bp + kc*512);
    const short8 bl = *(const short8*)(bp + kc*512 + lod);
    acc = __builtin_amdgcn_mfma_f32_16x16x32_bf16(ahi, bh, acc, 0,0,0);
    acc = __builtin_amdgcn_mfma_f32_16x16x32_bf16(ahi, bl, acc, 0,0,0);
    acc = __builtin_amdgcn_mfma_f32_16x16x32_bf16(alo, bh, acc, 0,0,0);
  }
  const int row0 = w*16 + quad*4, col = bid*16 + m;
  #pragma unroll
  for (int r=0;r<4;r++)
    GR[(size_t)(row0 + r)*512 + col] = acc[r];
}

// =============== K4: pa2 — GAT2 (512 blocks, XCD-swizzled), A staged in LDS (2 halves) ===============
__global__ __launch_bounds__(512) void pa2_kernel(
    const uint_t* __restrict__ x2pk,
    const ushort_t* __restrict__ wl2Thi, const ushort_t* __restrict__ wl2Tlo,
    const float* __restrict__ GR,
    const float* __restrict__ att2, const float* __restrict__ bias2,
    const unsigned* __restrict__ adjw, const int* __restrict__ aiw,
    float* __restrict__ X3)
{
  __shared__ __align__(16) uint_t s_a[8192];    // 32KB: A half (8 kc x 2 rows x 512), swizzled
  __shared__ __align__(16) float s_gl[32*132];
  __shared__ __align__(16) float s_p2[128];
  __shared__ __align__(16) float s_at[128];
  __shared__ __align__(16) float s_bb[128];
  __shared__ float s_lg[32];
  __shared__ float s_al[32];
  const int t = threadIdx.x, bid = blockIdx.x;
  // XCD swizzle: same-sample blocks 128 apart -> same XCD
  const int s = bid & 127, h = bid >> 7;
  const int w = t>>6, lane = t&63, m = lane&15, quad = lane>>4;
  (void)lane;
  const int ai = aiw[s];
  const unsigned arow = adjw[s*32+ai];

  if (t < 128){
    s_p2[t] = GR[(size_t)s*512 + h*128 + t];
    s_at[t] = att2[h*128+t];
    s_bb[t] = bias2[h*128+t];
  }

  // gl2 = x2 @ wl2 : each wave owns one 16-col tile for full K=512, A from LDS.
  const ushort_t* bq = wl2Thi + (size_t)(h*8 + w)*8192 + m*32 + quad*8;
  const size_t lod = (size_t)(wl2Tlo - wl2Thi);
  const int sw = (m*32 + quad*8) ^ ((m&7)<<2);
  floatx4 acc0 = (floatx4){0.f,0.f,0.f,0.f}, acc1 = acc0;

  #pragma unroll
  for (int half=0; half<2; half++){
    // cooperative stage: 8192 words, 16 per thread (4 x uint4), swizzled
    #pragma unroll
    for (int j=0;j<4;j++){
      const int W = t*16 + j*4;
      const int kcl = W>>10, rp = (W>>9)&1, u = W&511;
      const int du = u ^ (((u>>5)&7)<<2);
      *(uint4*)&s_a[kcl*1024 + rp*512 + du] =
        *(const uint4*)(x2pk + (size_t)(s*2+rp)*8192 + (size_t)(half*8+kcl)*512 + u);
    }
    __syncthreads();
    #pragma unroll 4
    for (int kcl=0; kcl<8; kcl++){
      const int kc = half*8 + kcl;
      const uint4 u00 = *(const uint4*)&s_a[kcl*1024 + sw];
      const uint4 u01 = *(const uint4*)&s_a[kcl*1024 + (sw^4)];
      const uint4 u10 = *(const uint4*)&s_a[kcl*1024 + 512 + sw];
      const uint4 u11 = *(const uint4*)&s_a[kcl*1024 + 512 + (sw^4)];
      short8 ahi0, alo0, ahi1, alo1;
      UNPACK8(u00,u01,ahi0,alo0)
      UNPACK8(u10,u11,ahi1,alo1)
      const short8 bh = *(const short8*)(bq + kc*512);
      const short8 bl = *(const short8*)(bq + kc*512 + lod);
      acc0 = __builtin_amdgcn_mfma_f32_16x16x32_bf16(ahi0, bh, acc0, 0,0,0);
      acc0 = __builtin_amdgcn_mfma_f32_16x16x32_bf16(ahi0, bl, acc0, 0,0,0);
      acc0 = __builtin_amdgcn_mfma_f32_16x16x32_bf16(alo0, bh, acc0, 0,0,0);
      acc1 = __builtin_amdgcn_mfma_f32_16x16x32_bf16(ahi1, bh, acc1, 0,0,0);
      acc1 = __builtin_amdgcn_mfma_f32_16x16x32_bf16(ahi1, bl, acc1, 0,0,0);
      acc1 = __builtin_amdgcn_mfma_f32_16x16x32_bf16(alo1, bh, acc1, 0,0,0);
    }
    __syncthreads();
  }
  {
    const int col = w*16 + m;
    #pragma unroll
    for (int r=0;r<4;r++){
      s_gl[(quad*4+r)*132 + col]    = acc0[r];
      s_gl[(16+quad*4+r)*132 + col] = acc1[r];
    }
  }
  __syncthreads();

  if (t < 256){
    const int j = t>>3, pq = t&7;
    float sum = 0.f;
    #pragma unroll
    for (int q=0;q<4;q++){
      const int c = pq*16 + q*4;
      const float4 g = *(const float4*)&s_gl[j*132 + c];
      const float4 r = *(const float4*)&s_p2[c];
      const float4 a = *(const float4*)&s_at[c];
      float e0 = r.x+g.x; e0 = fmaxf(e0, 0.2f*e0);
      float e1 = r.y+g.y; e1 = fmaxf(e1, 0.2f*e1);
      float e2 = r.z+g.z; e2 = fmaxf(e2, 0.2f*e2);
      float e3 = r.w+g.w; e3 = fmaxf(e3, 0.2f*e3);
      sum += e0*a.x + e1*a.y + e2*a.z + e3*a.w;
    }
    sum += __shfl_xor(sum,1,64);
    sum += __shfl_xor(sum,2,64);
    sum += __shfl_xor(sum,4,64);
    if (pq==0) s_lg[j] = sum;
  }
  __syncthreads();
  if (t < 32){
    const float lg = s_lg[t];
    const bool ok = (arow>>t)&1u;
    float v = ok ? lg : -3.0e38f;
    #pragma unroll
    for (int d_=16; d_; d_>>=1) v = fmaxf(v, __shfl_xor(v, d_, 32));
    const float e = ok ? __expf(lg - v) : 0.f;
    float sm = e;
    #pragma unroll
    for (int d_=16; d_; d_>>=1) sm += __shfl_xor(sm, d_, 32);
    s_al[t] = e / sm;
  }
  __syncthreads();
  if (t < 128){
    float acc2 = 0.f;
    #pragma unroll 8
    for (int j=0;j<32;j++) acc2 += s_al[j] * s_gl[j*132 + t];
    X3[(size_t)s*512 + h*128 + t] = fmaxf(acc2 + s_bb[t], 0.f);
  }
}

// =============== K5: hepi — per-sample: k<640 partial sums + x3 GEMV (K=512) + combine ===============
__global__ __launch_bounds__(512) void hepi_kernel(
    const float* __restrict__ X3, const float* __restrict__ hpart,
    const float* __restrict__ q_w1, const float* __restrict__ q_b1,
    const float* __restrict__ q_w2, const float* __restrict__ q_b2,
    const float* __restrict__ v_w1, const float* __restrict__ v_b1,
    const float* __restrict__ v_w2, const float* __restrict__ v_b2,
    float* __restrict__ out)
{
  __shared__ __align__(16) float s_x3[512];
  __shared__ float s_p6[8*6];
  const int t = threadIdx.x, s = blockIdx.x;
  const int w = t>>6, lane = t&63;

  s_x3[t] = X3[(size_t)s*512 + t];
  __syncthreads();

  // col t: 0..255 q, 256..511 v (matches hpart layout)
  float val;
  {
    const int col = t & 255;
    float acc = (t < 256) ? q_b1[col] : v_b1[col];
    #pragma unroll
    for (int ks=0; ks<4; ks++)
      acc += hpart[(size_t)ks*65536 + (size_t)s*512 + t];
    const float* Wp = ((t < 256) ? q_w1 : v_w1) + (size_t)640*256 + col;
    #pragma unroll 8
    for (int k=0;k<512;k++) acc += s_x3[k] * Wp[(size_t)k*256];
    val = fmaxf(acc, 0.f);
  }

  // dueling combine
  float p[6];
  #pragma unroll
  for (int o=0;o<6;o++) p[o] = 0.f;
  if (t < 256){
    #pragma unroll
    for (int o=0;o<5;o++) p[o] = val * q_w2[t*5+o];
  } else {
    p[5] = val * v_w2[t-256];
  }
  #pragma unroll
  for (int d_=32; d_; d_>>=1){
    #pragma unroll
    for (int o=0;o<6;o++) p[o] += __shfl_xor(p[o], d_, 64);
  }
  if (lane==0){
    #pragma unroll
    for (int o=0;o<6;o++) s_p6[w*6+o] = p[o];
  }
  __syncthreads();
  if (t < 6){
    float v = 0.f;
    #pragma unroll
    for (int ww=0; ww<8; ww++) v += s_p6[ww*6 + t];
    s_p6[t] = v;
  }
  __syncthreads();
  if (t < 5){
    const float q0 = s_p6[0]+q_b2[0], q1 = s_p6[1]+q_b2[1], q2 = s_p6[2]+q_b2[2],
                q3 = s_p6[3]+q_b2[3], q4 = s_p6[4]+q_b2[4];
    const float mean = (q0+q1+q2+q3+q4) / 5.0f;
    const float v = s_p6[5] + v_b2[0];
    const float qt = (t==0?q0:t==1?q1:t==2?q2:t==3?q3:q4);
    out[s*5+t] = qt - mean + v;
  }
}

extern "C" void kernel_launch(void* const* d_in, const int* in_sizes, int n_in,
                              void* d_out, int out_size, void* d_ws, size_t ws_size,
                              hipStream_t stream) {
  (void)n_in; (void)out_size; (void)ws_size;
  const float* obs    = (const float*)d_in[0];
  const float* enc_w1 = (const float*)d_in[1];
  const float* enc_b1 = (const float*)d_in[2];
  const float* enc_w2 = (const float*)d_in[3];
  const float* enc_b2 = (const float*)d_in[4];
  const float* wl1    = (const float*)d_in[5];
  const float* wr1    = (const float*)d_in[6];
  const float* att1   = (const float*)d_in[7];
  const float* bias1  = (const float*)d_in[8];
  const float* wl2    = (const float*)d_in[9];
  const float* wr2    = (const float*)d_in[10];
  const float* att2   = (const float*)d_in[11];
  const float* bias2  = (const float*)d_in[12];
  const float* q_w1   = (const float*)d_in[13];
  const float* q_b1   = (const float*)d_in[14];
  const float* q_w2   = (const float*)d_in[15];
  const float* q_b2   = (const float*)d_in[16];
  const float* v_w1   = (const float*)d_in[17];
  const float* v_b1   = (const float*)d_in[18];
  const float* v_w2   = (const float*)d_in[19];
  const float* v_b2   = (const float*)d_in[20];

  // Workspace layout (total ~17.6 MB; ws is ~268 MB per harness fill)
  char* ws = (char*)d_ws;
  uint_t*   x_pk    = (uint_t*)  (ws + 0);           // 2,097,152
  uint_t*   xcat_pk = (uint_t*)  (ws + 2097152);     //   589,824
  unsigned* adjw    = (unsigned*)(ws + 2686976);     //    16,384
  int*      aiw     = (int*)     (ws + 2703360);     //       512
  uint_t*   x2_pk   = (uint_t*)  (ws + 2703872);     // 8,388,608
  ushort_t* wl1Thi  = (ushort_t*)(ws + 11092480);    //   131,072
  ushort_t* wl1Tlo  = (ushort_t*)(ws + 11223552);    //   131,072
  ushort_t* wr1Thi  = (ushort_t*)(ws + 11354624);    //   131,072
  ushort_t* wr1Tlo  = (ushort_t*)(ws + 11485696);    //   131,072
  ushort_t* wl2Thi  = (ushort_t*)(ws + 11616768);    //   524,288
  ushort_t* wl2Tlo  = (ushort_t*)(ws + 12141056);    //   524,288
  ushort_t* qw1Thi  = (ushort_t*)(ws + 12665344);    //   589,824
  ushort_t* qw1Tlo  = (ushort_t*)(ws + 13255168);    //   589,824
  ushort_t* vw1Thi  = (ushort_t*)(ws + 13844992);    //   589,824
  ushort_t* vw1Tlo  = (ushort_t*)(ws + 14434816);    //   589,824
  ushort_t* wr2Thi  = (ushort_t*)(ws + 15024640);    //   524,288
  ushort_t* wr2Tlo  = (ushort_t*)(ws + 15548928);    //   524,288
  float*    GR      = (float*)   (ws + 16073216);    //   262,144
  float*    hpart   = (float*)   (ws + 16335360);    // 1,048,576 (4 slots)
  float*    X3      = (float*)   (ws + 17383936);    //   262,144 (ends 17,646,080)

  prep_kernel<<<512 + 960, 256, 0, stream>>>(obs, enc_w1, enc_b1, enc_w2, enc_b2,
      wl1, wr1, wl2, wr2, q_w1, v_w1,
      wl1Thi, wl1Tlo, wr1Thi, wr1Tlo, wl2Thi, wl2Tlo, wr2Thi, wr2Tlo,
      qw1Thi, qw1Tlo, vw1Thi, vw1Tlo,
      x_pk, xcat_pk, adjw, aiw);

  pa1_kernel<<<512, 512, 0, stream>>>(x_pk, wl1Thi, wl1Tlo, wr1Thi, wr1Tlo,
      att1, bias1, adjw, aiw, x2_pk, xcat_pk);

  gr2_kernel<<<64, 512, 0, stream>>>(xcat_pk, wr2Thi, wr2Tlo,
      qw1Thi, qw1Tlo, vw1Thi, vw1Tlo, hpart, GR);

  pa2_kernel<<<512, 512, 0, stream>>>(x2_pk, wl2Thi, wl2Tlo, GR,
      att2, bias2, adjw, aiw, X3);

  hepi_kernel<<<128, 512, 0, stream>>>(X3, hpart,
      q_w1, q_b1, q_w2, q_b2, v_w1, v_b1, v_w2, v_b2,
      (float*)d_out);
}

// Round 9
// 161.283 us; speedup vs baseline: 5.9949x; 1.0846x over previous
//
#include <hip/hip_runtime.h>
#include <hip/hip_bf16.h>

typedef unsigned int uint_t;
typedef unsigned short ushort_t;
typedef __attribute__((ext_vector_type(8))) short short8;
typedef __attribute__((ext_vector_type(4))) float floatx4;

__device__ __forceinline__ float4 fma4(float4 a, float s, float4 w){
  a.x += s*w.x; a.y += s*w.y; a.z += s*w.z; a.w += s*w.w; return a;
}
__device__ __forceinline__ float4 relu4(float4 a){
  return make_float4(fmaxf(a.x,0.f),fmaxf(a.y,0.f),fmaxf(a.z,0.f),fmaxf(a.w,0.f));
}
__device__ __forceinline__ unsigned bf16rne(float f){
  unsigned u = __float_as_uint(f);
  return (u + 0x7fffu + ((u>>16)&1u)) >> 16;
}
__device__ __forceinline__ uint_t packbf(float f){
  unsigned hb = bf16rne(f);
  float hf = __uint_as_float(hb<<16);
  unsigned lb = bf16rne(f - hf);
  return (hb<<16) | lb;
}
__device__ __forceinline__ uint4 pack4(float4 v){
  uint4 u; u.x=packbf(v.x); u.y=packbf(v.y); u.z=packbf(v.z); u.w=packbf(v.w); return u;
}
__device__ __forceinline__ float unpk(uint_t u){
  return __uint_as_float(u & 0xffff0000u) + __uint_as_float(u<<16);
}
#define UNPACK8(u0,u1,hi,lo) \
  hi[0]=(short)(u0.x>>16); lo[0]=(short)u0.x; \
  hi[1]=(short)(u0.y>>16); lo[1]=(short)u0.y; \
  hi[2]=(short)(u0.z>>16); lo[2]=(short)u0.z; \
  hi[3]=(short)(u0.w>>16); lo[3]=(short)u0.w; \
  hi[4]=(short)(u1.x>>16); lo[4]=(short)u1.x; \
  hi[5]=(short)(u1.y>>16); lo[5]=(short)u1.y; \
  hi[6]=(short)(u1.z>>16); lo[6]=(short)u1.z; \
  hi[7]=(short)(u1.w>>16); lo[7]=(short)u1.w;

// Fragment-order offset: off(n,k) = (n>>4)*16*K + (k>>5)*512 + (n&15)*32 + (k&31)
// LDS A-stage swizzle (bank-conflict fix): word u within a 512-word row is stored at
//   u ^ (((u>>5)&7)<<2).  Read base sw = (m*32+quad*8) ^ ((m&7)<<2); second uint4 at sw^4.

// heads GEMM K-window body: job (ks, ct in 0..7), 512 threads (8 waves = 8 row-blocks).
template<int NKC>
__device__ __forceinline__ void hgemm_body(
    const uint_t* __restrict__ xcatpk,
    const ushort_t* __restrict__ qw1Thi, const ushort_t* __restrict__ qw1Tlo,
    const ushort_t* __restrict__ vw1Thi, const ushort_t* __restrict__ vw1Tlo,
    float* __restrict__ part, int ks, int ct, int t, int k0c, int slot0)
{
  const int w = t>>6, lane = t&63, m = lane&15, quad = lane>>4;
  const ushort_t* Bhi = (ct<4) ? qw1Thi : vw1Thi;
  const int cbl = (ct<4) ? ct*64 : (ct-4)*64;
  const int cbg = (ct<4) ? ct*64 : 256 + (ct-4)*64;
  const int kb = k0c + ks*NKC;
  const uint_t* ap = xcatpk + (size_t)w*18432 + m*32 + quad*8 + (size_t)kb*512;
  const ushort_t* bp0 = Bhi + (size_t)((cbl>>4)+0)*18432 + m*32 + quad*8 + (size_t)kb*512;
  const ushort_t* bp1 = Bhi + (size_t)((cbl>>4)+1)*18432 + m*32 + quad*8 + (size_t)kb*512;
  const ushort_t* bp2 = Bhi + (size_t)((cbl>>4)+2)*18432 + m*32 + quad*8 + (size_t)kb*512;
  const ushort_t* bp3 = Bhi + (size_t)((cbl>>4)+3)*18432 + m*32 + quad*8 + (size_t)kb*512;
  const size_t lod = (size_t)(qw1Tlo - qw1Thi);
  floatx4 acc[4];
  #pragma unroll
  for (int i=0;i<4;i++) acc[i] = (floatx4){0.f,0.f,0.f,0.f};
  #pragma unroll
  for (int kc=0; kc<NKC; kc++){
    const uint4 ua0 = *(const uint4*)(ap);
    const uint4 ua1 = *(const uint4*)(ap+4);
    ap += 512;
    short8 ahi, alo;
    UNPACK8(ua0,ua1,ahi,alo)
    const ushort_t* bps[4] = {bp0, bp1, bp2, bp3};
    #pragma unroll
    for (int nt=0; nt<4; nt++){
      const short8 bh = *(const short8*)(bps[nt] + kc*512);
      const short8 bl = *(const short8*)(bps[nt] + kc*512 + lod);
      acc[nt] = __builtin_amdgcn_mfma_f32_16x16x32_bf16(ahi, bh, acc[nt], 0,0,0);
      acc[nt] = __builtin_amdgcn_mfma_f32_16x16x32_bf16(ahi, bl, acc[nt], 0,0,0);
      acc[nt] = __builtin_amdgcn_mfma_f32_16x16x32_bf16(alo, bh, acc[nt], 0,0,0);
    }
  }
  float* pdst = part + (size_t)(slot0+ks)*65536;
  const int crow0 = w*16 + quad*4;
  #pragma unroll
  for (int nt=0; nt<4; nt++){
    const int col = cbg + nt*16 + m;
    #pragma unroll
    for (int r=0;r<4;r++)
      pdst[(size_t)(crow0 + r)*512 + col] = acc[nt][r];
  }
}

// =============== K1: enc (blocks 0..511, XCD-swizzled) + ALL weight converts (512..1471) ===============
__global__ __launch_bounds__(256) void prep_kernel(
    const float* __restrict__ obs,
    const float* __restrict__ enc_w1, const float* __restrict__ enc_b1,
    const float* __restrict__ enc_w2, const float* __restrict__ enc_b2,
    const float* __restrict__ wl1, const float* __restrict__ wr1,
    const float* __restrict__ wl2, const float* __restrict__ wr2,
    const float* __restrict__ q_w1, const float* __restrict__ v_w1,
    ushort_t* __restrict__ wl1Thi, ushort_t* __restrict__ wl1Tlo,
    ushort_t* __restrict__ wr1Thi, ushort_t* __restrict__ wr1Tlo,
    ushort_t* __restrict__ wl2Thi, ushort_t* __restrict__ wl2Tlo,
    ushort_t* __restrict__ wr2Thi, ushort_t* __restrict__ wr2Tlo,
    ushort_t* __restrict__ qw1Thi, ushort_t* __restrict__ qw1Tlo,
    ushort_t* __restrict__ vw1Thi, ushort_t* __restrict__ vw1Tlo,
    uint_t* __restrict__ xpk, uint_t* __restrict__ xcatpk,
    unsigned* __restrict__ adjw, int* __restrict__ aiw)
{
  const int t = threadIdx.x, bid = blockIdx.x;
  if (bid >= 512){
    __shared__ float sm[32][33];
    const int cw = bid - 512;
    const float* in; ushort_t* ohi; ushort_t* olo; int K, N, tt, ktiles;
    if (cw < 64)       { in=wl1;  ohi=wl1Thi; olo=wl1Tlo; K=128;  N=512; tt=cw;     ktiles=4;  }
    else if (cw < 128) { in=wr1;  ohi=wr1Thi; olo=wr1Tlo; K=128;  N=512; tt=cw-64;  ktiles=4;  }
    else if (cw < 384) { in=wl2;  ohi=wl2Thi; olo=wl2Tlo; K=512;  N=512; tt=cw-128; ktiles=16; }
    else if (cw < 640) { in=wr2;  ohi=wr2Thi; olo=wr2Tlo; K=512;  N=512; tt=cw-384; ktiles=16; }
    else if (cw < 800) { in=q_w1; ohi=qw1Thi; olo=qw1Tlo; K=1152; N=256; tt=cw-640; ktiles=20; }  // rows<640 only
    else               { in=v_w1; ohi=vw1Thi; olo=vw1Tlo; K=1152; N=256; tt=cw-800; ktiles=20; }  // rows<640 only
    const int kt = tt % ktiles, nt = tt / ktiles;
    const int r = t>>5, c = t&31;
    #pragma unroll
    for (int i=0;i<4;i++)
      sm[r+i*8][c] = in[(size_t)(kt*32 + r + i*8)*N + nt*32 + c];
    __syncthreads();
    #pragma unroll
    for (int i=0;i<4;i++){
      const int nl = r + i*8;
      const int n  = nt*32 + nl;
      const float f = sm[c][nl];
      const unsigned hb = bf16rne(f);
      const float hf = __uint_as_float(hb<<16);
      const unsigned lb = bf16rne(f - hf);
      const size_t off = (size_t)(n>>4)*(size_t)(16*K) + (size_t)kt*512 + (size_t)(n&15)*32 + c;
      ohi[off] = (ushort_t)hb;
      olo[off] = (ushort_t)lb;
    }
    return;
  }
  __shared__ float s_pos[64];
  __shared__ float s_feats[128];
  __shared__ __align__(16) float s_h[8*132];
  __shared__ int s_ai;
  // XCD swizzle: same-sample blocks 128 apart -> same XCD (bid%8 preserved)
  const int s = bid & 127, g = bid >> 7;
  const float* ob = obs + s*577;

  if (t==0){
    float a = ob[576];
    a = fminf(fmaxf(a, 0.f), 31.f);
    s_ai = (int)a;
    if (g==0) aiw[s] = (int)a;
  }
  if (t < 128){ const int n=t>>4, f=t&15; s_feats[t] = ob[(g*8+n)*18+2+f]; }
  if (g==0 && t>=128 && t<192){ const int u=t-128; s_pos[u] = ob[(u>>1)*18 + (u&1)]; }
  __syncthreads();

  if (g==0 && t < 32){
    const float px = s_pos[2*t], py = s_pos[2*t+1];
    const float R2 = 0.09f;
    unsigned mm = 0u;
    for (int j=0;j<32;j++){
      const float dx = __fsub_rn(px, s_pos[2*j]), dy = __fsub_rn(py, s_pos[2*j+1]);
      const float d2 = __fadd_rn(__fmul_rn(dx,dx), __fmul_rn(dy,dy));
      if (d2 <= R2 || j==t) mm |= (1u<<j);
    }
    adjw[s*32+t] = mm;
  }

  const int n = t>>5, c0 = (t&31)*4;
  {
    float4 a = *(const float4*)(enc_b1+c0);
    #pragma unroll
    for (int f=0; f<16; f++)
      a = fma4(a, s_feats[n*16+f], *(const float4*)(enc_w1 + f*128 + c0));
    *(float4*)&s_h[n*132+c0] = relu4(a);
  }
  __syncthreads();
  {
    float4 a = *(const float4*)(enc_b2+c0);
    #pragma unroll 4
    for (int k=0;k<128;k+=4){
      const float4 hv = *(const float4*)&s_h[n*132+k];
      a = fma4(a, hv.x, *(const float4*)(enc_w2 + (k+0)*128 + c0));
      a = fma4(a, hv.y, *(const float4*)(enc_w2 + (k+1)*128 + c0));
      a = fma4(a, hv.z, *(const float4*)(enc_w2 + (k+2)*128 + c0));
      a = fma4(a, hv.w, *(const float4*)(enc_w2 + (k+3)*128 + c0));
    }
    a = relu4(a);
    const uint4 p = pack4(a);
    const int i = g*8 + n;
    uint_t* xp = xpk + (size_t)(s*2 + (i>>4))*2048 + (c0>>5)*512 + (i&15)*32 + (c0&31);
    *(uint4*)xp = p;
    if (i == s_ai){
      uint_t* xc = xcatpk + (size_t)(s>>4)*18432 + (c0>>5)*512 + (s&15)*32 + (c0&31);
      *(uint4*)xc = p;
    }
  }
}

// =============== K2: pa1 — GAT1 (512 blocks, XCD-swizzled), A staged in LDS ===============
__global__ __launch_bounds__(512) void pa1_kernel(
    const uint_t* __restrict__ xpk,
    const ushort_t* __restrict__ wl1Thi, const ushort_t* __restrict__ wl1Tlo,
    const ushort_t* __restrict__ wr1Thi, const ushort_t* __restrict__ wr1Tlo,
    const float* __restrict__ att, const float* __restrict__ bias,
    const unsigned* __restrict__ adjw, const int* __restrict__ aiw,
    uint_t* __restrict__ x2pk, uint_t* __restrict__ xcatpk)
{
  __shared__ __align__(16) uint_t s_ax[4096];   // 16KB: A = xpk[s] (4 kc x 2 rows x 512), swizzled
  __shared__ __align__(16) float s_gl[32*132];
  __shared__ __align__(16) float s_gr[32*132];
  __shared__ __align__(16) float s_att[128];
  __shared__ __align__(16) float s_b[128];
  __shared__ float s_lg[32*33];
  __shared__ unsigned s_adj[32];
  const int t = threadIdx.x, bid = blockIdx.x;

  // XCD swizzle: same-sample blocks 128 apart -> same XCD
  const int s = bid & 127, h = bid >> 7;
  const int w = t>>6, lane = t&63, m = lane&15, quad = lane>>4;
  const int mat = w>>2, cpair = w&3;   // mat: 0=gl(wl1), 1=gr(wr1); cpair: 32-col chunk

  if (t < 128){ s_att[t] = att[h*128 + t]; s_b[t] = bias[h*128 + t]; }
  if (t >= 224 && t < 256) s_adj[t-224] = adjw[s*32 + (t-224)];
  const int ai = aiw[s];

  // cooperative A stage: 4096 words, 8 per thread (2 x uint4), swizzled
  #pragma unroll
  for (int j=0;j<2;j++){
    const int W = t*8 + j*4;
    const int kcl = W>>10, rp = (W>>9)&1, u = W&511;
    const int du = u ^ (((u>>5)&7)<<2);
    *(uint4*)&s_ax[kcl*1024 + rp*512 + du] =
      *(const uint4*)(xpk + (size_t)(s*2+rp)*2048 + (size_t)kcl*512 + u);
  }

  const ushort_t* Bhi = (mat==0) ? wl1Thi : wr1Thi;
  const ushort_t* Blo = (mat==0) ? wl1Tlo : wr1Tlo;
  const int nbase = h*8 + cpair*2;
  const ushort_t* bp0 = Bhi + (size_t)(nbase+0)*2048 + m*32 + quad*8;
  const ushort_t* bp1 = Bhi + (size_t)(nbase+1)*2048 + m*32 + quad*8;
  const size_t lod = (size_t)(Blo - Bhi);
  const int sw = (m*32 + quad*8) ^ ((m&7)<<2);
  floatx4 acc[2][2];
  #pragma unroll
  for (int i=0;i<2;i++)
    #pragma unroll
    for (int j=0;j<2;j++) acc[i][j] = (floatx4){0.f,0.f,0.f,0.f};

  __syncthreads();

  #pragma unroll
  for (int kc=0; kc<4; kc++){
    const uint4 u00 = *(const uint4*)&s_ax[kc*1024 + sw];
    const uint4 u01 = *(const uint4*)&s_ax[kc*1024 + (sw^4)];
    const uint4 u10 = *(const uint4*)&s_ax[kc*1024 + 512 + sw];
    const uint4 u11 = *(const uint4*)&s_ax[kc*1024 + 512 + (sw^4)];
    short8 ahi0, alo0, ahi1, alo1;
    UNPACK8(u00,u01,ahi0,alo0)
    UNPACK8(u10,u11,ahi1,alo1)
    const ushort_t* bps[2] = {bp0, bp1};
    #pragma unroll
    for (int nt=0; nt<2; nt++){
      const short8 bh = *(const short8*)(bps[nt] + kc*512);
      const short8 bl = *(const short8*)(bps[nt] + kc*512 + lod);
      acc[0][nt] = __builtin_amdgcn_mfma_f32_16x16x32_bf16(ahi0, bh, acc[0][nt], 0,0,0);
      acc[0][nt] = __builtin_amdgcn_mfma_f32_16x16x32_bf16(ahi0, bl, acc[0][nt], 0,0,0);
      acc[0][nt] = __builtin_amdgcn_mfma_f32_16x16x32_bf16(alo0, bh, acc[0][nt], 0,0,0);
      acc[1][nt] = __builtin_amdgcn_mfma_f32_16x16x32_bf16(ahi1, bh, acc[1][nt], 0,0,0);
      acc[1][nt] = __builtin_amdgcn_mfma_f32_16x16x32_bf16(ahi1, bl, acc[1][nt], 0,0,0);
      acc[1][nt] = __builtin_amdgcn_mfma_f32_16x16x32_bf16(alo1, bh, acc[1][nt], 0,0,0);
    }
  }
  {
    float* dst = mat ? s_gr : s_gl;
    const int colbase = cpair*32;
    #pragma unroll
    for (int nt=0; nt<2; nt++){
      const int col = colbase + nt*16 + m;
      #pragma unroll
      for (int r=0;r<4;r++){
        dst[(quad*4+r)*132 + col]      = acc[0][nt][r];
        dst[(16+quad*4+r)*132 + col]   = acc[1][nt][r];
      }
    }
  }
  __syncthreads();

  // logits
  {
    const int i = t>>4, jb = t&15;
    float lacc[2] = {0.f,0.f};
    for (int c=0;c<128;c+=4){
      const float4 g = *(const float4*)&s_gr[i*132+c];
      const float4 a = *(const float4*)&s_att[c];
      #pragma unroll
      for (int mm=0;mm<2;mm++){
        const float4 gj = *(const float4*)&s_gl[(jb+16*mm)*132 + c];
        float ex = g.x+gj.x; ex = fmaxf(ex, 0.2f*ex);
        float ey = g.y+gj.y; ey = fmaxf(ey, 0.2f*ey);
        float ez = g.z+gj.z; ez = fmaxf(ez, 0.2f*ez);
        float ew = g.w+gj.w; ew = fmaxf(ew, 0.2f*ew);
        lacc[mm] += ex*a.x + ey*a.y + ez*a.z + ew*a.w;
      }
    }
    s_lg[i*33 + jb]      = lacc[0];
    s_lg[i*33 + jb + 16] = lacc[1];
  }
  __syncthreads();

  // masked softmax
  #pragma unroll
  for (int rnd=0; rnd<2; rnd++){
    const int i = rnd*16 + (t>>5), j = t&31;
    const float lg = s_lg[i*33+j];
    const bool ok = (s_adj[i]>>j)&1u;
    float v = ok ? lg : -3.0e38f;
    #pragma unroll
    for (int d_=16; d_; d_>>=1) v = fmaxf(v, __shfl_xor(v, d_, 32));
    const float e = ok ? __expf(lg - v) : 0.f;
    float sum = e;
    #pragma unroll
    for (int d_=16; d_; d_>>=1) sum += __shfl_xor(sum, d_, 32);
    s_lg[i*33+j] = e / sum;
  }
  __syncthreads();

  // aggregate -> packed x2 + agent tap
  {
    const int i = t>>4, c0 = (t&15)*8;
    float4 o0 = make_float4(0.f,0.f,0.f,0.f), o1 = o0;
    for (int j=0;j<32;j++){
      const float al = s_lg[i*33+j];
      o0 = fma4(o0, al, *(const float4*)&s_gl[j*132 + c0]);
      o1 = fma4(o1, al, *(const float4*)&s_gl[j*132 + c0 + 4]);
    }
    const float4 b0 = *(const float4*)&s_b[c0];
    const float4 b1 = *(const float4*)&s_b[c0+4];
    o0 = relu4(make_float4(o0.x+b0.x, o0.y+b0.y, o0.z+b0.z, o0.w+b0.w));
    o1 = relu4(make_float4(o1.x+b1.x, o1.y+b1.y, o1.z+b1.z, o1.w+b1.w));
    const uint4 p0 = pack4(o0), p1 = pack4(o1);
    const int kb = h*128 + c0;
    uint_t* xp = x2pk + (size_t)(s*2 + (i>>4))*8192 + (kb>>5)*512 + (i&15)*32 + (kb&31);
    *(uint4*)&xp[0] = p0;
    *(uint4*)&xp[4] = p1;
    if (i == ai){
      const int kk = 128 + kb;
      uint_t* tp = xcatpk + (size_t)(s>>4)*18432 + (kk>>5)*512 + (s&15)*32 + (kk&31);
      *(uint4*)&tp[0] = p0;
      *(uint4*)&tp[4] = p1;
    }
  }
}

// =============== K3: pa2 — GR prologue + GAT2 + hp3 GEMV (blocks 0..511)
//                 + heads-GEMM k<640 partials (blocks 512..543) ===============
__global__ __launch_bounds__(512) void pa2_kernel(
    const uint_t* __restrict__ x2pk, const uint_t* __restrict__ xcatpk,
    const ushort_t* __restrict__ wl2Thi, const ushort_t* __restrict__ wl2Tlo,
    const ushort_t* __restrict__ wr2Thi, const ushort_t* __restrict__ wr2Tlo,
    const ushort_t* __restrict__ qw1Thi, const ushort_t* __restrict__ qw1Tlo,
    const ushort_t* __restrict__ vw1Thi, const ushort_t* __restrict__ vw1Tlo,
    const float* __restrict__ att2, const float* __restrict__ bias2,
    const unsigned* __restrict__ adjw, const int* __restrict__ aiw,
    const float* __restrict__ q_w1, const float* __restrict__ v_w1,
    float* __restrict__ hpart, float* __restrict__ hp3)
{
  __shared__ __align__(16) uint_t s_a[8192];    // 32KB staging (GR A, then x2 halves), swizzled
  __shared__ __align__(16) float s_gl[32*132];
  __shared__ __align__(16) float s_p2[128];
  __shared__ __align__(16) float s_at[128];
  __shared__ __align__(16) float s_bb[128];
  __shared__ float s_lg[32];
  __shared__ float s_al[32];
  const int t = threadIdx.x, bid = blockIdx.x;

  if (bid >= 512){
    const int hk = bid - 512;      // 0..31: ks = hk>>3, ct = hk&7 — k<640 partials
    hgemm_body<5>(xcatpk, qw1Thi, qw1Tlo, vw1Thi, vw1Tlo, hpart, hk>>3, hk&7, t, 0, 0);
    return;
  }

  // XCD swizzle: same-sample blocks 128 apart -> same XCD
  const int s = bid & 127, h = bid >> 7;
  const int w = t>>6, lane = t&63, m = lane&15, quad = lane>>4;
  (void)lane;
  const int ai = aiw[s];
  const unsigned arow = adjw[s*32+ai];
  const int sw = (m*32 + quad*8) ^ ((m&7)<<2);

  if (t < 128){ s_at[t] = att2[h*128+t]; s_bb[t] = bias2[h*128+t]; }

  // ---- GR prologue: p2 = (X2_agent @ wr2)[s, h*128..+128) via MFMA ----
  // stage xcat tap (rows rt*16..+16, k in [128,640)): 8192 words, swizzled
  {
    const int rt = s >> 4;
    #pragma unroll
    for (int j=0;j<4;j++){
      const int W = t*16 + j*4;
      const int kcl = W>>9, u = W&511;
      const int du = u ^ (((u>>5)&7)<<2);
      *(uint4*)&s_a[kcl*512 + du] =
        *(const uint4*)(xcatpk + (size_t)rt*18432 + (size_t)(4+kcl)*512 + u);
    }
  }
  __syncthreads();
  {
    const int ct = h*8 + w;                       // wave's 16-col GR tile
    const ushort_t* bp = wr2Thi + (size_t)ct*8192 + m*32 + quad*8;
    const size_t lodr = (size_t)(wr2Tlo - wr2Thi);
    floatx4 acc = (floatx4){0.f,0.f,0.f,0.f};
    #pragma unroll 4
    for (int kc=0; kc<16; kc++){
      const uint4 ua0 = *(const uint4*)&s_a[kc*512 + sw];
      const uint4 ua1 = *(const uint4*)&s_a[kc*512 + (sw^4)];
      short8 ahi, alo;
      UNPACK8(ua0,ua1,ahi,alo)
      const short8 bh = *(const short8*)(bp + kc*512);
      const short8 bl = *(const short8*)(bp + kc*512 + lodr);
      acc = __builtin_amdgcn_mfma_f32_16x16x32_bf16(ahi, bh, acc, 0,0,0);
      acc = __builtin_amdgcn_mfma_f32_16x16x32_bf16(ahi, bl, acc, 0,0,0);
      acc = __builtin_amdgcn_mfma_f32_16x16x32_bf16(alo, bh, acc, 0,0,0);
    }
    #pragma unroll
    for (int r=0;r<4;r++)
      s_gl[(quad*4+r)*132 + w*16 + m] = acc[r];
  }
  __syncthreads();
  if (t < 128) s_p2[t] = s_gl[(s&15)*132 + t];
  __syncthreads();

  // ---- gl2 = x2 @ wl2 : A staged in LDS (2 halves) ----
  const ushort_t* bq = wl2Thi + (size_t)(h*8 + w)*8192 + m*32 + quad*8;
  const size_t lod = (size_t)(wl2Tlo - wl2Thi);
  floatx4 acc0 = (floatx4){0.f,0.f,0.f,0.f}, acc1 = acc0;

  #pragma unroll
  for (int half=0; half<2; half++){
    #pragma unroll
    for (int j=0;j<4;j++){
      const int W = t*16 + j*4;
      const int kcl = W>>10, rp = (W>>9)&1, u = W&511;
      const int du = u ^ (((u>>5)&7)<<2);
      *(uint4*)&s_a[kcl*1024 + rp*512 + du] =
        *(const uint4*)(x2pk + (size_t)(s*2+rp)*8192 + (size_t)(half*8+kcl)*512 + u);
    }
    __syncthreads();
    #pragma unroll 4
    for (int kcl=0; kcl<8; kcl++){
      const int kc = half*8 + kcl;
      const uint4 u00 = *(const uint4*)&s_a[kcl*1024 + sw];
      const uint4 u01 = *(const uint4*)&s_a[kcl*1024 + (sw^4)];
      const uint4 u10 = *(const uint4*)&s_a[kcl*1024 + 512 + sw];
      const uint4 u11 = *(const uint4*)&s_a[kcl*1024 + 512 + (sw^4)];
      short8 ahi0, alo0, ahi1, alo1;
      UNPACK8(u00,u01,ahi0,alo0)
      UNPACK8(u10,u11,ahi1,alo1)
      const short8 bh = *(const short8*)(bq + kc*512);
      const short8 bl = *(const short8*)(bq + kc*512 + lod);
      acc0 = __builtin_amdgcn_mfma_f32_16x16x32_bf16(ahi0, bh, acc0, 0,0,0);
      acc0 = __builtin_amdgcn_mfma_f32_16x16x32_bf16(ahi0, bl, acc0, 0,0,0);
      acc0 = __builtin_amdgcn_mfma_f32_16x16x32_bf16(alo0, bh, acc0, 0,0,0);
      acc1 = __builtin_amdgcn_mfma_f32_16x16x32_bf16(ahi1, bh, acc1, 0,0,0);
      acc1 = __builtin_amdgcn_mfma_f32_16x16x32_bf16(ahi1, bl, acc1, 0,0,0);
      acc1 = __builtin_amdgcn_mfma_f32_16x16x32_bf16(alo1, bh, acc1, 0,0,0);
    }
    __syncthreads();
  }
  {
    const int col = w*16 + m;
    #pragma unroll
    for (int r=0;r<4;r++){
      s_gl[(quad*4+r)*132 + col]    = acc0[r];
      s_gl[(16+quad*4+r)*132 + col] = acc1[r];
    }
  }
  __syncthreads();

  // logits
  if (t < 256){
    const int j = t>>3, pq = t&7;
    float sum = 0.f;
    #pragma unroll
    for (int q=0;q<4;q++){
      const int c = pq*16 + q*4;
      const float4 g = *(const float4*)&s_gl[j*132 + c];
      const float4 r = *(const float4*)&s_p2[c];
      const float4 a = *(const float4*)&s_at[c];
      float e0 = r.x+g.x; e0 = fmaxf(e0, 0.2f*e0);
      float e1 = r.y+g.y; e1 = fmaxf(e1, 0.2f*e1);
      float e2 = r.z+g.z; e2 = fmaxf(e2, 0.2f*e2);
      float e3 = r.w+g.w; e3 = fmaxf(e3, 0.2f*e3);
      sum += e0*a.x + e1*a.y + e2*a.z + e3*a.w;
    }
    sum += __shfl_xor(sum,1,64);
    sum += __shfl_xor(sum,2,64);
    sum += __shfl_xor(sum,4,64);
    if (pq==0) s_lg[j] = sum;
  }
  __syncthreads();
  if (t < 32){
    const float lg = s_lg[t];
    const bool ok = (arow>>t)&1u;
    float v = ok ? lg : -3.0e38f;
    #pragma unroll
    for (int d_=16; d_; d_>>=1) v = fmaxf(v, __shfl_xor(v, d_, 32));
    const float e = ok ? __expf(lg - v) : 0.f;
    float sm = e;
    #pragma unroll
    for (int d_=16; d_; d_>>=1) sm += __shfl_xor(sm, d_, 32);
    s_al[t] = e / sm;
  }
  __syncthreads();
  // x3 slice -> s_p2 (reuse; logits phase done)
  if (t < 128){
    float acc2 = 0.f;
    #pragma unroll 8
    for (int j=0;j<32;j++) acc2 += s_al[j] * s_gl[j*132 + t];
    s_p2[t] = fmaxf(acc2 + s_bb[t], 0.f);
  }
  __syncthreads();

  // hp3 GEMV: x3 slice's contribution to heads layer-1 (col = t: 0..255 q, 256..511 v)
  {
    const float* Wm = (t < 256) ? q_w1 : v_w1;
    const int col = t & 255;
    const float* wp = Wm + (size_t)(640 + h*128)*256 + col;
    float acc3 = 0.f;
    #pragma unroll 8
    for (int k=0;k<128;k++) acc3 += s_p2[k] * wp[(size_t)k*256];
    hp3[((size_t)h*128 + s)*512 + t] = acc3;
  }
}

// =============== K4: hepi — sum 4 hpart + 4 hp3 + dueling combine (128 x 256) ===============
__global__ __launch_bounds__(256) void hepi_kernel(
    const float* __restrict__ hpart, const float* __restrict__ hp3,
    const float* __restrict__ q_b1, const float* __restrict__ q_w2, const float* __restrict__ q_b2,
    const float* __restrict__ v_b1, const float* __restrict__ v_w2, const float* __restrict__ v_b2,
    float* __restrict__ out)
{
  __shared__ float s_p[4*6];
  const int t = threadIdx.x, s = blockIdx.x;
  float hq = q_b1[t], hv = v_b1[t];
  #pragma unroll
  for (int ks=0; ks<4; ks++){
    hq += hpart[(size_t)ks*65536 + (size_t)s*512 + t];
    hv += hpart[(size_t)ks*65536 + (size_t)s*512 + 256 + t];
  }
  #pragma unroll
  for (int h=0; h<4; h++){
    hq += hp3[((size_t)h*128 + s)*512 + t];
    hv += hp3[((size_t)h*128 + s)*512 + 256 + t];
  }
  hq = fmaxf(hq, 0.f);
  hv = fmaxf(hv, 0.f);
  float p[6];
  #pragma unroll
  for (int o=0;o<5;o++) p[o] = hq * q_w2[t*5+o];
  p[5] = hv * v_w2[t];
  #pragma unroll
  for (int d_=32; d_; d_>>=1){
    #pragma unroll
    for (int o=0;o<6;o++) p[o] += __shfl_xor(p[o], d_, 64);
  }
  const int w = t>>6, lane = t&63;
  if (lane==0){
    #pragma unroll
    for (int o=0;o<6;o++) s_p[w*6+o] = p[o];
  }
  __syncthreads();
  if (t < 6) s_p[t] = s_p[t] + s_p[6+t] + s_p[12+t] + s_p[18+t];
  __syncthreads();
  if (t < 5){
    const float q0 = s_p[0]+q_b2[0], q1 = s_p[1]+q_b2[1], q2 = s_p[2]+q_b2[2],
                q3 = s_p[3]+q_b2[3], q4 = s_p[4]+q_b2[4];
    const float mean = (q0+q1+q2+q3+q4) / 5.0f;
    const float v = s_p[5] + v_b2[0];
    const float qt = (t==0?q0:t==1?q1:t==2?q2:t==3?q3:q4);
    out[s*5+t] = qt - mean + v;
  }
}

extern "C" void kernel_launch(void* const* d_in, const int* in_sizes, int n_in,
                              void* d_out, int out_size, void* d_ws, size_t ws_size,
                              hipStream_t stream) {
  (void)n_in; (void)out_size; (void)ws_size;
  const float* obs    = (const float*)d_in[0];
  const float* enc_w1 = (const float*)d_in[1];
  const float* enc_b1 = (const float*)d_in[2];
  const float* enc_w2 = (const float*)d_in[3];
  const float* enc_b2 = (const float*)d_in[4];
  const float* wl1    = (const float*)d_in[5];
  const float* wr1    = (const float*)d_in[6];
  const float* att1   = (const float*)d_in[7];
  const float* bias1  = (const float*)d_in[8];
  const float* wl2    = (const float*)d_in[9];
  const float* wr2    = (const float*)d_in[10];
  const float* att2   = (const float*)d_in[11];
  const float* bias2  = (const float*)d_in[12];
  const float* q_w1   = (const float*)d_in[13];
  const float* q_b1   = (const float*)d_in[14];
  const float* q_w2   = (const float*)d_in[15];
  const float* q_b2   = (const float*)d_in[16];
  const float* v_w1   = (const float*)d_in[17];
  const float* v_b1   = (const float*)d_in[18];
  const float* v_w2   = (const float*)d_in[19];
  const float* v_b2   = (const float*)d_in[20];

  // Workspace layout (total ~18.2 MB; ws is ~268 MB per harness fill)
  char* ws = (char*)d_ws;
  uint_t*   x_pk    = (uint_t*)  (ws + 0);           // 2,097,152
  uint_t*   xcat_pk = (uint_t*)  (ws + 2097152);     //   589,824
  unsigned* adjw    = (unsigned*)(ws + 2686976);     //    16,384
  int*      aiw     = (int*)     (ws + 2703360);     //       512
  uint_t*   x2_pk   = (uint_t*)  (ws + 2703872);     // 8,388,608
  ushort_t* wl1Thi  = (ushort_t*)(ws + 11092480);    //   131,072
  ushort_t* wl1Tlo  = (ushort_t*)(ws + 11223552);    //   131,072
  ushort_t* wr1Thi  = (ushort_t*)(ws + 11354624);    //   131,072
  ushort_t* wr1Tlo  = (ushort_t*)(ws + 11485696);    //   131,072
  ushort_t* wl2Thi  = (ushort_t*)(ws + 11616768);    //   524,288
  ushort_t* wl2Tlo  = (ushort_t*)(ws + 12141056);    //   524,288
  ushort_t* qw1Thi  = (ushort_t*)(ws + 12665344);    //   589,824
  ushort_t* qw1Tlo  = (ushort_t*)(ws + 13255168);    //   589,824
  ushort_t* vw1Thi  = (ushort_t*)(ws + 13844992);    //   589,824
  ushort_t* vw1Tlo  = (ushort_t*)(ws + 14434816);    //   589,824
  ushort_t* wr2Thi  = (ushort_t*)(ws + 15024640);    //   524,288
  ushort_t* wr2Tlo  = (ushort_t*)(ws + 15548928);    //   524,288
  float*    hpart   = (float*)   (ws + 16073216);    // 1,048,576 (4 slots)
  float*    hp3     = (float*)   (ws + 17121792);    // 1,048,576 (ends 18,170,368)

  prep_kernel<<<512 + 960, 256, 0, stream>>>(obs, enc_w1, enc_b1, enc_w2, enc_b2,
      wl1, wr1, wl2, wr2, q_w1, v_w1,
      wl1Thi, wl1Tlo, wr1Thi, wr1Tlo, wl2Thi, wl2Tlo, wr2Thi, wr2Tlo,
      qw1Thi, qw1Tlo, vw1Thi, vw1Tlo,
      x_pk, xcat_pk, adjw, aiw);

  pa1_kernel<<<512, 512, 0, stream>>>(x_pk, wl1Thi, wl1Tlo, wr1Thi, wr1Tlo,
      att1, bias1, adjw, aiw, x2_pk, xcat_pk);

  pa2_kernel<<<512 + 32, 512, 0, stream>>>(x2_pk, xcat_pk,
      wl2Thi, wl2Tlo, wr2Thi, wr2Tlo,
      qw1Thi, qw1Tlo, vw1Thi, vw1Tlo,
      att2, bias2, adjw, aiw, q_w1, v_w1,
      hpart, hp3);

  hepi_kernel<<<128, 256, 0, stream>>>(hpart, hp3,
      q_b1, q_w2, q_b2, v_b1, v_w2, v_b2,
      (float*)d_out);
}